// Round 5
// baseline (365.885 us; speedup 1.0000x reference)
//
#include <hip/hip_runtime.h>
#include <hip/hip_bf16.h>

namespace {

constexpr int kB = 1024;      // batch
constexpr int kNU = 1024;     // num users
constexpr int kNB = 2048;     // num businesses
constexpr int kNN = 3072;     // total nodes
constexpr int kE = 16384;     // raw edges
constexpr int kET = kE + kNN; // edges + self loops = 19456
constexpr int kH = 768;
constexpr int kHeads = 8;
constexpr int kSplitK = 4;    // GAT2 split-K factor

typedef __attribute__((ext_vector_type(8))) short bf16x8_t;
typedef __attribute__((ext_vector_type(4))) float f32x4_t;

__device__ __forceinline__ float tof(float x) { return x; }
__device__ __forceinline__ float tof(__hip_bfloat16 x) { return __bfloat162float(x); }
__device__ __forceinline__ void stor(float* p, float v) { *p = v; }
__device__ __forceinline__ void stor(__hip_bfloat16* p, float v) { *p = __float2bfloat16(v); }

__device__ __forceinline__ float blo(unsigned u) {
  union { unsigned u; float f; } c; c.u = u << 16; return c.f;
}
__device__ __forceinline__ float bhi(unsigned u) {
  union { unsigned u; float f; } c; c.u = u & 0xffff0000u; return c.f;
}

__device__ __forceinline__ void gload_lds16(const void* g, void* l) {
  __builtin_amdgcn_global_load_lds(
      (const __attribute__((address_space(1))) void*)g,
      (__attribute__((address_space(3))) void*)l, 16, 0, 0);
}

// =======================================================================
// 256x256 / BK=64 / 8-wave counted-vmcnt GEMM (T2 swizzle + T3/T4 + T5)
// A: [M,K] bf16 row-major; Bt: [N,K] bf16 row-major.
// 8 waves as 2(m) x 4(n); wave output 128x64; acc[8][4] f32x4.
// LDS: 2 buf x (A 32KB + B 32KB) = 128 KiB.
// Per K-tile(64): entry vmcnt(8)+bar -> reads+2 quadrants -> lgkm0+bar ->
//                 stage(t+2 -> same buf) -> 2 quadrants.  Never drains mid-loop.
// =======================================================================
template <int SPLITK>
__global__ __launch_bounds__(512, 2) void gemm8(
    const __hip_bfloat16* __restrict__ A, const __hip_bfloat16* __restrict__ Bt,
    const float* __restrict__ bias, __hip_bfloat16* __restrict__ Cb,
    float* __restrict__ Cf, int M, int N, int K, int KC, int act) {
  __shared__ __align__(16) char ldsA[2][32768];
  __shared__ __align__(16) char ldsB[2][32768];
  const int t = threadIdx.x;
  const int w = t >> 6, lane = t & 63;
  const int wm = w >> 2, wn = w & 3;
  const int lr = lane & 15, lg = lane >> 4;
  // bijective XCD swizzle (m204 formula; works for any nwg)
  const int gx = gridDim.x, gy = gridDim.y;
  const int nwg = gx * gy;
  const int orig = blockIdx.y * gx + blockIdx.x;
  const int q = nwg >> 3, r8 = nwg & 7;
  const int xcd = orig & 7, lid = orig >> 3;
  const int s = (xcd < r8 ? xcd * (q + 1) : r8 * (q + 1) + (xcd - r8) * q) + lid;
  const int by = s % gy, bx = s / gy;
  const int bm = by * 256, bn = bx * 256;
  const int kbeg = blockIdx.z * KC;
  const int NT = KC >> 6;

  // pre-swizzled staging source (linear LDS dest; source permuted so that
  // reader's  lds_byte = linear ^ ((row&7)<<4)  finds the right data)
  int sRow[4], sCol[4];
#pragma unroll
  for (int c = 0; c < 4; ++c) {
    int L = (c * 512 + t) * 16;
    int P = L ^ (((L >> 7) & 7) << 4);
    sRow[c] = P >> 7;
    sCol[c] = (P & 127) >> 1;
  }

  auto stage = [&](int buf, int kt) {
    const int k0 = kbeg + (kt << 6);
#pragma unroll
    for (int c = 0; c < 4; ++c)
      gload_lds16(A + (size_t)(bm + sRow[c]) * K + k0 + sCol[c],
                  ldsA[buf] + c * 8192 + w * 1024);
#pragma unroll
    for (int c = 0; c < 4; ++c)
      gload_lds16(Bt + (size_t)(bn + sRow[c]) * K + k0 + sCol[c],
                  ldsB[buf] + c * 8192 + w * 1024);
  };

  const int xr = (lr & 7) << 4;
  auto rdA = [&](int buf, int mf, int ks) {
    int byte = (wm * 128 + mf * 16 + lr) * 128 + ks * 64 + lg * 16;
    return *(const bf16x8_t*)(ldsA[buf] + (byte ^ xr));
  };
  auto rdB = [&](int buf, int nf, int ks) {
    int byte = (wn * 64 + nf * 16 + lr) * 128 + ks * 64 + lg * 16;
    return *(const bf16x8_t*)(ldsB[buf] + (byte ^ xr));
  };

  f32x4_t acc[8][4];
#pragma unroll
  for (int i = 0; i < 8; ++i)
#pragma unroll
    for (int j = 0; j < 4; ++j) acc[i][j] = (f32x4_t){0.f, 0.f, 0.f, 0.f};

  stage(0, 0);
  if (NT > 1) stage(1, 1);

  for (int kt = 0; kt < NT; ++kt) {
    const int b = kt & 1;
    // counted wait: keep the newest 8 (tile kt+1's) in flight; drain only at last tile
    if (kt + 1 < NT) asm volatile("s_waitcnt vmcnt(8)" ::: "memory");
    else             asm volatile("s_waitcnt vmcnt(0)" ::: "memory");
    __builtin_amdgcn_sched_barrier(0);
    asm volatile("s_barrier" ::: "memory");

    bf16x8_t a0[4][2], a1[4][2], b0[2][2], b1[2][2];
#pragma unroll
    for (int mf = 0; mf < 4; ++mf)
#pragma unroll
      for (int ks = 0; ks < 2; ++ks) a0[mf][ks] = rdA(b, mf, ks);
#pragma unroll
    for (int nf = 0; nf < 2; ++nf)
#pragma unroll
      for (int ks = 0; ks < 2; ++ks) b0[nf][ks] = rdB(b, nf, ks);
    __builtin_amdgcn_s_setprio(1);
#pragma unroll
    for (int mf = 0; mf < 4; ++mf)
#pragma unroll
      for (int nf = 0; nf < 2; ++nf)
#pragma unroll
        for (int ks = 0; ks < 2; ++ks)
          acc[mf][nf] = __builtin_amdgcn_mfma_f32_16x16x32_bf16(
              a0[mf][ks], b0[nf][ks], acc[mf][nf], 0, 0, 0);
    __builtin_amdgcn_s_setprio(0);

#pragma unroll
    for (int mf = 0; mf < 4; ++mf)
#pragma unroll
      for (int ks = 0; ks < 2; ++ks) a1[mf][ks] = rdA(b, mf + 4, ks);
#pragma unroll
    for (int nf = 0; nf < 2; ++nf)
#pragma unroll
      for (int ks = 0; ks < 2; ++ks) b1[nf][ks] = rdB(b, nf + 2, ks);
    __builtin_amdgcn_s_setprio(1);
#pragma unroll
    for (int mf = 0; mf < 4; ++mf)
#pragma unroll
      for (int nf = 0; nf < 2; ++nf)
#pragma unroll
        for (int ks = 0; ks < 2; ++ks)
          acc[mf][nf + 2] = __builtin_amdgcn_mfma_f32_16x16x32_bf16(
              a0[mf][ks], b1[nf][ks], acc[mf][nf + 2], 0, 0, 0);
    __builtin_amdgcn_s_setprio(0);

    // all this wave's ds_reads of buf b complete, then block-wide sync:
    // after this barrier NO wave will read buf b for tile kt again
    asm volatile("s_waitcnt lgkmcnt(0)" ::: "memory");
    __builtin_amdgcn_sched_barrier(0);
    asm volatile("s_barrier" ::: "memory");

    if (kt + 2 < NT) stage(b, kt + 2);  // overwrite buf b with tile kt+2
    __builtin_amdgcn_sched_barrier(0);

    __builtin_amdgcn_s_setprio(1);
#pragma unroll
    for (int mf = 0; mf < 4; ++mf)
#pragma unroll
      for (int nf = 0; nf < 2; ++nf)
#pragma unroll
        for (int ks = 0; ks < 2; ++ks) {
          acc[mf + 4][nf] = __builtin_amdgcn_mfma_f32_16x16x32_bf16(
              a1[mf][ks], b0[nf][ks], acc[mf + 4][nf], 0, 0, 0);
          acc[mf + 4][nf + 2] = __builtin_amdgcn_mfma_f32_16x16x32_bf16(
              a1[mf][ks], b1[nf][ks], acc[mf + 4][nf + 2], 0, 0, 0);
        }
    __builtin_amdgcn_s_setprio(0);
  }

  const int col0 = bn + wn * 64;
  if constexpr (SPLITK != 0) {
    float* Cp = Cf + (size_t)blockIdx.z * M * N;
#pragma unroll
    for (int mf = 0; mf < 8; ++mf) {
      const int row0 = bm + wm * 128 + mf * 16 + lg * 4;
#pragma unroll
      for (int nf = 0; nf < 4; ++nf) {
        const int cn = col0 + nf * 16 + lr;
#pragma unroll
        for (int rr = 0; rr < 4; ++rr)
          Cp[(size_t)(row0 + rr) * N + cn] = acc[mf][nf][rr];
      }
    }
  } else {
#pragma unroll
    for (int mf = 0; mf < 8; ++mf) {
      const int row0 = bm + wm * 128 + mf * 16 + lg * 4;
#pragma unroll
      for (int nf = 0; nf < 4; ++nf) {
        const int cn = col0 + nf * 16 + lr;
        const float bvv = bias ? bias[cn] : 0.f;
#pragma unroll
        for (int rr = 0; rr < 4; ++rr) {
          float v = acc[mf][nf][rr] + bvv;
          if (act) v = fmaxf(v, 0.f);
          Cb[(size_t)(row0 + rr) * N + cn] = __float2bfloat16(v);
        }
      }
    }
  }
}

// ---------------- 2-phase GEMM (proven) for the small problems ----------------
template <int BM, int BN, int FM, int FN, typename TC>
__device__ __forceinline__ void gemm_body(
    const __hip_bfloat16* __restrict__ A, const __hip_bfloat16* __restrict__ Bt,
    const float* __restrict__ bias, TC* __restrict__ C,
    int M, int N, int K, int act, int bx, int by) {
  __shared__ __align__(16) __hip_bfloat16 As[2][BM][32];
  __shared__ __align__(16) __hip_bfloat16 Bs[2][BN][32];
  const int t = threadIdx.x;
  const int w = t >> 6, lane = t & 63;
  const int wm = w >> 1, wn = w & 1;
  const int bm = by * BM, bn = bx * BN;
  const int lr = lane & 15, lg = lane >> 4;

  f32x4_t acc[FM][FN];
#pragma unroll
  for (int m = 0; m < FM; ++m)
#pragma unroll
    for (int n = 0; n < FN; ++n) acc[m][n] = (f32x4_t){0.f, 0.f, 0.f, 0.f};

  auto stage = [&](int buf, int kt) {
    const int k0 = kt << 5;
#pragma unroll
    for (int i = 0; i < BM / 64; ++i) {
      int L = i * 256 + t;
      gload_lds16(A + (size_t)(bm + (L >> 2)) * K + k0 + (L & 3) * 8,
                  (char*)(&As[buf][0][0]) + ((size_t)(i * 256 + w * 64)) * 16);
    }
#pragma unroll
    for (int i = 0; i < BN / 64; ++i) {
      int L = i * 256 + t;
      gload_lds16(Bt + (size_t)(bn + (L >> 2)) * K + k0 + (L & 3) * 8,
                  (char*)(&Bs[buf][0][0]) + ((size_t)(i * 256 + w * 64)) * 16);
    }
  };

  const int NT = K >> 5;
  stage(0, 0);
  __syncthreads();
  for (int kt = 0; kt < NT; ++kt) {
    const int cur = kt & 1;
    if (kt + 1 < NT) stage(cur ^ 1, kt + 1);
    bf16x8_t af[FM], bv[FN];
#pragma unroll
    for (int m = 0; m < FM; ++m)
      af[m] = *(const bf16x8_t*)&As[cur][wm * FM * 16 + m * 16 + lr][lg * 8];
#pragma unroll
    for (int n = 0; n < FN; ++n)
      bv[n] = *(const bf16x8_t*)&Bs[cur][wn * FN * 16 + n * 16 + lr][lg * 8];
#pragma unroll
    for (int m = 0; m < FM; ++m)
#pragma unroll
      for (int n = 0; n < FN; ++n)
        acc[m][n] = __builtin_amdgcn_mfma_f32_16x16x32_bf16(af[m], bv[n], acc[m][n], 0, 0, 0);
    __syncthreads();
  }

#pragma unroll
  for (int m = 0; m < FM; ++m) {
    const int row0 = bm + wm * FM * 16 + m * 16 + lg * 4;
#pragma unroll
    for (int n = 0; n < FN; ++n) {
      const int cn = bn + wn * FN * 16 + n * 16 + lr;
      const float bvv = bias ? bias[cn] : 0.f;
#pragma unroll
      for (int r = 0; r < 4; ++r) {
        float v = acc[m][n][r] + bvv;
        if (act) v = fmaxf(v, 0.f);
        stor(&C[(size_t)(row0 + r) * N + cn], v);
      }
    }
  }
}

__device__ __forceinline__ void swz_xy(bool mfast, int& bx, int& by) {
  const int nwg = gridDim.x * gridDim.y;
  const int orig = blockIdx.y * gridDim.x + blockIdx.x;
  const int swz = (orig & 7) * (nwg >> 3) + (orig >> 3);
  if (mfast) { by = swz % gridDim.y; bx = swz / gridDim.y; }
  else       { bx = swz % gridDim.x; by = swz / gridDim.x; }
}

template <int BM, int BN, int FM, int FN, typename TC, bool MFAST>
__global__ __launch_bounds__(256) void mfma_gemm(
    const __hip_bfloat16* __restrict__ A, const __hip_bfloat16* __restrict__ Bt,
    const float* __restrict__ bias, TC* __restrict__ C,
    int M, int N, int K, int act) {
  int bx, by;
  swz_xy(MFAST, bx, by);
  gemm_body<BM, BN, FM, FN, TC>(A, Bt, bias, C, M, N, K, act, bx, by);
}

template <int BM, int BN, int FM, int FN>
__global__ __launch_bounds__(256) void mfma_gemm_dual(
    const __hip_bfloat16* __restrict__ A0, const __hip_bfloat16* __restrict__ Bt0,
    const float* __restrict__ bias0, float* __restrict__ C0,
    const __hip_bfloat16* __restrict__ A1, const __hip_bfloat16* __restrict__ Bt1,
    const float* __restrict__ bias1, float* __restrict__ C1,
    int M, int N, int K) {
  int bx, by;
  swz_xy(true, bx, by);
  const __hip_bfloat16* A = blockIdx.z ? A1 : A0;
  const __hip_bfloat16* Bt = blockIdx.z ? Bt1 : Bt0;
  const float* bias = blockIdx.z ? bias1 : bias0;
  float* C = blockIdx.z ? C1 : C0;
  gemm_body<BM, BN, FM, FN, float>(A, Bt, bias, C, M, N, K, 0, bx, by);
}

__global__ void splitk_reduce_kernel(const float* __restrict__ part,
                                     __hip_bfloat16* __restrict__ outb, int MN4, int S) {
  int i = blockIdx.x * 256 + threadIdx.x;
  if (i >= MN4) return;
  float4 s = ((const float4*)part)[i];
  for (int z = 1; z < S; ++z) {
    float4 p = ((const float4*)part)[(size_t)z * MN4 + i];
    s.x += p.x; s.y += p.y; s.z += p.z; s.w += p.w;
  }
  __hip_bfloat16* o = outb + (size_t)i * 4;
  o[0] = __float2bfloat16(s.x); o[1] = __float2bfloat16(s.y);
  o[2] = __float2bfloat16(s.z); o[3] = __float2bfloat16(s.w);
}

// ---------------- batched transpose+convert: f32 [K][N] -> bf16 [N][K] ----------------
struct TJobs {
  const float* in[6];
  __hip_bfloat16* out[6];
  int K[6];
  int N[6];
  int start[7];
};

__global__ __launch_bounds__(256) void transp_all_kernel(TJobs j) {
  __shared__ float tl[32][33];
  const int bid = blockIdx.x;
  int idx = 0;
#pragma unroll
  for (int q = 1; q < 6; ++q)
    if (bid >= j.start[q]) idx = q;
  const int tile = bid - j.start[idx];
  const int N = j.N[idx], K = j.K[idx];
  const int tilesN = N >> 5;
  const int n0 = (tile % tilesN) << 5, k0 = (tile / tilesN) << 5;
  const float* in = j.in[idx];
  __hip_bfloat16* out = j.out[idx];
  const int t = threadIdx.x;
  const int r = t >> 3, c = (t & 7) * 4;
#pragma unroll
  for (int i = 0; i < 4; ++i) tl[r][c + i] = in[(size_t)(k0 + r) * N + n0 + c + i];
  __syncthreads();
  __hip_bfloat16* op = out + (size_t)(n0 + r) * K + k0 + c;
#pragma unroll
  for (int i = 0; i < 4; ++i) op[i] = __float2bfloat16(tl[c + i][r]);
}

// ---------------- input prep ----------------
__global__ void prep_inputs_kernel(const float* __restrict__ text_cls,
                                   const float* __restrict__ img_cls,
                                   __hip_bfloat16* __restrict__ text_bf,
                                   __hip_bfloat16* __restrict__ imgm_bf) {
  int idx = blockIdx.x * 256 + threadIdx.x;
  if (idx >= kB * kH) return;
  text_bf[idx] = __float2bfloat16(text_cls[idx]);
  int b = idx / kH, c = idx - b * kH;
  const float* p = img_cls + (size_t)b * 3 * kH + c;
  imgm_bf[idx] = __float2bfloat16((p[0] + p[kH] + p[2 * kH]) * (1.f / 3.f));
}

// ---------------- degree count + winner (merged) ----------------
__global__ void deg_winner_kernel(const int* __restrict__ ei, int* __restrict__ deg,
                                  const int* __restrict__ business_idx,
                                  int* __restrict__ winner) {
  int e = blockIdx.x * 256 + threadIdx.x;
  if (e < kET) {
    int dst = (e < kE) ? ei[kE + e] : (e - kE);
    atomicAdd(&deg[dst], 1);
  }
  if (e < kB) atomicMax(&winner[business_idx[e] - kNU], e);
}

__global__ __launch_bounds__(1024) void scan_kernel(const int* __restrict__ deg,
                                                    int* __restrict__ rowptr,
                                                    int* __restrict__ cursor) {
  __shared__ int sums[1024];
  int t = threadIdx.x;
  int v0 = deg[t * 3], v1 = deg[t * 3 + 1], v2 = deg[t * 3 + 2];
  int s = v0 + v1 + v2;
  sums[t] = s;
  __syncthreads();
  for (int o = 1; o < 1024; o <<= 1) {
    int xv = (t >= o) ? sums[t - o] : 0;
    __syncthreads();
    sums[t] += xv;
    __syncthreads();
  }
  int excl = sums[t] - s;
  rowptr[t * 3] = excl;          cursor[t * 3] = excl;
  rowptr[t * 3 + 1] = excl + v0; cursor[t * 3 + 1] = excl + v0;
  rowptr[t * 3 + 2] = excl + v0 + v1; cursor[t * 3 + 2] = excl + v0 + v1;
  if (t == 1023) rowptr[kNN] = excl + s;
}

__global__ void fill_kernel(const int* __restrict__ ei, int* __restrict__ cursor,
                            int* __restrict__ cols) {
  int e = blockIdx.x * 256 + threadIdx.x;
  if (e >= kET) return;
  int src, dst;
  if (e < kE) { src = ei[e]; dst = ei[kE + e]; } else { src = dst = e - kE; }
  int pos = atomicAdd(&cursor[dst], 1);
  cols[pos] = src;
}

// ---------------- node feature build ----------------
__global__ void build_x_kernel(const int* __restrict__ user_idx,
                               const float* __restrict__ user_table,
                               const int* __restrict__ winner,
                               const float* __restrict__ text_emb,
                               const float* __restrict__ img_emb,
                               const float* __restrict__ biz_feats,
                               const float* __restrict__ W_bf,
                               const float* __restrict__ b_bf,
                               const float* __restrict__ biz_table,
                               __hip_bfloat16* __restrict__ xb) {
  int b = blockIdx.x;
  if (b < kNU) {
    int node = user_idx[b];
    for (int c = threadIdx.x; c < kH; c += blockDim.x)
      xb[(size_t)node * kH + c] = __float2bfloat16(user_table[(size_t)node * kH + c]);
  } else {
    int m = b - kNU;
    int w = winner[m];
    if (w < 0) return;
    int node = kNU + m;
    float f0 = biz_feats[w * 3], f1 = biz_feats[w * 3 + 1], f2 = biz_feats[w * 3 + 2];
    for (int c = threadIdx.x; c < kH; c += blockDim.x) {
      float meta = f0 * W_bf[c] + f1 * W_bf[kH + c] + f2 * W_bf[2 * kH + c] + b_bf[c];
      float v = (text_emb[(size_t)w * kH + c] + img_emb[(size_t)w * kH + c] + meta +
                 biz_table[(size_t)m * kH + c]) * 0.25f;
      xb[(size_t)node * kH + c] = __float2bfloat16(v);
    }
  }
}

// ---------------- attention scores ----------------
__global__ __launch_bounds__(256) void scores_kernel(
    const __hip_bfloat16* __restrict__ h, const float* __restrict__ att_src,
    const float* __restrict__ att_dst, float* __restrict__ s_src,
    float* __restrict__ s_dst, int total, int heads) {
  int gw = (blockIdx.x * 256 + threadIdx.x) >> 6;
  int lane = threadIdx.x & 63;
  if (gw >= total) return;
  int hd = gw % heads;
  const unsigned* hp = (const unsigned*)(h + (size_t)gw * kH);
  const float* as = att_src + (size_t)hd * kH;
  const float* ad = att_dst + (size_t)hd * kH;
  float ss = 0.f, sd = 0.f;
  for (int u = lane; u < kH / 2; u += 64) {
    unsigned v = hp[u];
    float f0 = blo(v), f1 = bhi(v);
    int c = u * 2;
    ss = fmaf(f0, as[c], fmaf(f1, as[c + 1], ss));
    sd = fmaf(f0, ad[c], fmaf(f1, ad[c + 1], sd));
  }
#pragma unroll
  for (int o = 32; o; o >>= 1) { ss += __shfl_down(ss, o); sd += __shfl_down(sd, o); }
  if (lane == 0) { s_src[gw] = ss; s_dst[gw] = sd; }
}

// ---------------- GAT segment softmax + aggregation (wave per (node,head)) ----------
__global__ __launch_bounds__(256) void gat_agg_kernel(
    const int* __restrict__ rowptr, const int* __restrict__ cols,
    const float* __restrict__ s_src, const float* __restrict__ s_dst,
    const __hip_bfloat16* __restrict__ h, const float* __restrict__ bias,
    int heads, int act, __hip_bfloat16* __restrict__ out_bf, float* __restrict__ out_f,
    int total) {
  const int pair = blockIdx.x * 4 + (threadIdx.x >> 6);
  if (pair >= total) return;
  const int lane = threadIdx.x & 63;
  const int n = pair / heads;
  const int hd = pair - n * heads;
  const int beg = rowptr[n], end = rowptr[n + 1];
  const float sdv = s_dst[pair];

  float m = -3.402823466e38f;
  for (int i = beg + lane; i < end; i += 64) {
    float e = s_src[(size_t)cols[i] * heads + hd] + sdv;
    e = (e > 0.f) ? e : 0.2f * e;
    m = fmaxf(m, e);
  }
#pragma unroll
  for (int o = 32; o; o >>= 1) m = fmaxf(m, __shfl_xor(m, o));

  float dsum = 0.f;
  for (int i = beg + lane; i < end; i += 64) {
    float e = s_src[(size_t)cols[i] * heads + hd] + sdv;
    e = (e > 0.f) ? e : 0.2f * e;
    dsum += expf(e - m);
  }
#pragma unroll
  for (int o = 32; o; o >>= 1) dsum += __shfl_xor(dsum, o);
  const float rdsum = 1.f / (dsum + 1e-16f);

  float a[12];
#pragma unroll
  for (int q = 0; q < 12; ++q) a[q] = 0.f;
  const size_t hs = (size_t)heads * kH;
  const size_t hoff = (size_t)hd * kH + (size_t)lane * 4;
  for (int i = beg; i < end; ++i) {
    int src = cols[i];
    float e = s_src[(size_t)src * heads + hd] + sdv;
    e = (e > 0.f) ? e : 0.2f * e;
    float wgt = expf(e - m) * rdsum;
    const __hip_bfloat16* hp = h + (size_t)src * hs + hoff;
#pragma unroll
    for (int j = 0; j < 3; ++j) {
      uint2 v = *(const uint2*)(hp + j * 256);
      a[j * 4 + 0] = fmaf(wgt, blo(v.x), a[j * 4 + 0]);
      a[j * 4 + 1] = fmaf(wgt, bhi(v.x), a[j * 4 + 1]);
      a[j * 4 + 2] = fmaf(wgt, blo(v.y), a[j * 4 + 2]);
      a[j * 4 + 3] = fmaf(wgt, bhi(v.y), a[j * 4 + 3]);
    }
  }
  const size_t ob = (size_t)n * hs + hoff;
  const size_t bb = (size_t)hd * kH + (size_t)lane * 4;
#pragma unroll
  for (int j = 0; j < 3; ++j) {
#pragma unroll
    for (int q = 0; q < 4; ++q) {
      float v = a[j * 4 + q] + bias[bb + j * 256 + q];
      if (act) v = fmaxf(v, 0.f);
      if (out_bf) out_bf[ob + j * 256 + q] = __float2bfloat16(v);
      else out_f[ob + j * 256 + q] = v;
    }
  }
}

// ---------------- MLP head ----------------
__global__ void cat_kernel(const float* __restrict__ xf, const float* __restrict__ text_emb,
                           const float* __restrict__ img_emb, const int* __restrict__ user_idx,
                           const int* __restrict__ business_idx, __hip_bfloat16* __restrict__ cat) {
  int b = blockIdx.x;
  int u = user_idx[b], z = business_idx[b];
  __hip_bfloat16* crow = cat + (size_t)b * 4 * kH;
  for (int c = threadIdx.x; c < kH; c += blockDim.x) {
    crow[c] = __float2bfloat16(xf[(size_t)u * kH + c]);
    crow[kH + c] = __float2bfloat16(xf[(size_t)z * kH + c]);
    crow[2 * kH + c] = __float2bfloat16(text_emb[(size_t)b * kH + c]);
    crow[3 * kH + c] = __float2bfloat16(img_emb[(size_t)b * kH + c]);
  }
}

__global__ __launch_bounds__(256) void final_kernel(const float* __restrict__ m2,
                                                    const float* __restrict__ Wf3,
                                                    const float* __restrict__ bf3,
                                                    float* __restrict__ out) {
  int b = (blockIdx.x * 256 + threadIdx.x) >> 6;
  int lane = threadIdx.x & 63;
  if (b >= kB) return;
  float s = 0.f;
  for (int c = lane; c < kH; c += 64) s = fmaf(m2[(size_t)b * kH + c], Wf3[c], s);
#pragma unroll
  for (int o = 32; o; o >>= 1) s += __shfl_down(s, o);
  if (lane == 0) out[b] = s + bf3[0];
}

}  // namespace

extern "C" void kernel_launch(void* const* d_in, const int* in_sizes, int n_in,
                              void* d_out, int out_size, void* d_ws, size_t ws_size,
                              hipStream_t stream) {
  const float* text_cls = (const float*)d_in[0];
  const float* img_cls = (const float*)d_in[1];
  const float* biz_feats = (const float*)d_in[2];
  const float* W_text = (const float*)d_in[3];
  const float* b_text = (const float*)d_in[4];
  const float* W_img = (const float*)d_in[5];
  const float* b_img = (const float*)d_in[6];
  const float* W_bf = (const float*)d_in[7];
  const float* b_bf = (const float*)d_in[8];
  const float* user_table = (const float*)d_in[9];
  const float* biz_table = (const float*)d_in[10];
  const float* W1 = (const float*)d_in[11];
  const float* att_src1 = (const float*)d_in[12];
  const float* att_dst1 = (const float*)d_in[13];
  const float* b1 = (const float*)d_in[14];
  const float* W2 = (const float*)d_in[15];
  const float* att_src2 = (const float*)d_in[16];
  const float* att_dst2 = (const float*)d_in[17];
  const float* b2 = (const float*)d_in[18];
  const float* Wf1 = (const float*)d_in[19];
  const float* bf1 = (const float*)d_in[20];
  const float* Wf2 = (const float*)d_in[21];
  const float* bf2 = (const float*)d_in[22];
  const float* Wf3 = (const float*)d_in[23];
  const float* bf3 = (const float*)d_in[24];
  const int* user_idx = (const int*)d_in[25];
  const int* business_idx = (const int*)d_in[26];
  const int* edge_index = (const int*)d_in[27];
  float* out = (float*)d_out;
  (void)in_sizes; (void)n_in; (void)out_size; (void)ws_size;

  char* base = (char*)d_ws;
  size_t off = 0;
  auto alloc = [&](size_t bytes) -> void* {
    void* p = base + off;
    off = (off + bytes + 255) & ~(size_t)255;
    return p;
  };
  __hip_bfloat16* xb = (__hip_bfloat16*)alloc((size_t)kNN * kH * 2);
  __hip_bfloat16* text_bf = (__hip_bfloat16*)alloc((size_t)kB * kH * 2);
  __hip_bfloat16* imgm_bf = (__hip_bfloat16*)alloc((size_t)kB * kH * 2);
  float* text_emb = (float*)alloc((size_t)kB * kH * 4);
  float* img_emb = (float*)alloc((size_t)kB * kH * 4);
  __hip_bfloat16* Wtt = (__hip_bfloat16*)alloc((size_t)kH * kH * 2);
  __hip_bfloat16* Wit = (__hip_bfloat16*)alloc((size_t)kH * kH * 2);
  __hip_bfloat16* W1t = (__hip_bfloat16*)alloc((size_t)kHeads * kH * kH * 2);
  __hip_bfloat16* W2t = (__hip_bfloat16*)alloc((size_t)kH * kHeads * kH * 2);
  __hip_bfloat16* Wf1t = (__hip_bfloat16*)alloc((size_t)2 * kH * 4 * kH * 2);
  __hip_bfloat16* Wf2t = (__hip_bfloat16*)alloc((size_t)kH * 2 * kH * 2);
  __hip_bfloat16* h1 = (__hip_bfloat16*)alloc((size_t)kNN * kHeads * kH * 2);
  __hip_bfloat16* x2 = (__hip_bfloat16*)alloc((size_t)kNN * kHeads * kH * 2);
  __hip_bfloat16* h2 = (__hip_bfloat16*)alloc((size_t)kNN * kH * 2);
  float* xf = (float*)alloc((size_t)kNN * kH * 4);
  float* s1s = (float*)alloc((size_t)kNN * kHeads * 4);
  float* s1d = (float*)alloc((size_t)kNN * kHeads * 4);
  float* s2s = (float*)alloc((size_t)kNN * 4);
  float* s2d = (float*)alloc((size_t)kNN * 4);
  __hip_bfloat16* catb = (__hip_bfloat16*)alloc((size_t)kB * 4 * kH * 2);
  __hip_bfloat16* m1 = (__hip_bfloat16*)alloc((size_t)kB * 2 * kH * 2);
  float* m2 = (float*)alloc((size_t)kB * kH * 4);
  int* deg = (int*)alloc((size_t)kNN * 4);
  int* rowptr = (int*)alloc((size_t)(kNN + 1) * 4);
  int* cursor = (int*)alloc((size_t)kNN * 4);
  int* cols = (int*)alloc((size_t)kET * 4);
  int* winner = (int*)alloc((size_t)kNB * 4);

  // split-K partials aliased over h1 (dead after scores1/agg1): exact fit for S=4
  float* part = (float*)h1;

  hipMemsetAsync(xb, 0, (size_t)kNN * kH * 2, stream);
  hipMemsetAsync(deg, 0, (size_t)kNN * 4, stream);
  hipMemsetAsync(winner, 0xFF, (size_t)kNB * 4, stream);

  // batched weight transposes
  TJobs tj;
  tj.in[0] = W_text; tj.out[0] = Wtt;  tj.K[0] = kH;          tj.N[0] = kH;
  tj.in[1] = W_img;  tj.out[1] = Wit;  tj.K[1] = kH;          tj.N[1] = kH;
  tj.in[2] = W1;     tj.out[2] = W1t;  tj.K[2] = kH;          tj.N[2] = kHeads * kH;
  tj.in[3] = W2;     tj.out[3] = W2t;  tj.K[3] = kHeads * kH; tj.N[3] = kH;
  tj.in[4] = Wf1;    tj.out[4] = Wf1t; tj.K[4] = 4 * kH;      tj.N[4] = 2 * kH;
  tj.in[5] = Wf2;    tj.out[5] = Wf2t; tj.K[5] = 2 * kH;      tj.N[5] = kH;
  tj.start[0] = 0;
  for (int q = 0; q < 6; ++q)
    tj.start[q + 1] = tj.start[q] + (tj.K[q] / 32) * (tj.N[q] / 32);
  transp_all_kernel<<<tj.start[6], 256, 0, stream>>>(tj);

  prep_inputs_kernel<<<(kB * kH + 255) / 256, 256, 0, stream>>>(text_cls, img_cls, text_bf,
                                                                imgm_bf);

  // encoders, batched in z
  mfma_gemm_dual<64, 64, 2, 2><<<dim3(kH / 64, kB / 64, 2), 256, 0, stream>>>(
      text_bf, Wtt, b_text, text_emb, imgm_bf, Wit, b_img, img_emb, kB, kH, kH);

  // CSR degree + winner
  deg_winner_kernel<<<(kET + 255) / 256, 256, 0, stream>>>(edge_index, deg, business_idx, winner);
  scan_kernel<<<1, 1024, 0, stream>>>(deg, rowptr, cursor);
  fill_kernel<<<(kET + 255) / 256, 256, 0, stream>>>(edge_index, cursor, cols);

  // node features
  build_x_kernel<<<kNN, 256, 0, stream>>>(user_idx, user_table, winner, text_emb, img_emb,
                                          biz_feats, W_bf, b_bf, biz_table, xb);

  // GAT layer 1 (8 heads): 8-wave counted-vmcnt engine, grid 24x12
  gemm8<0><<<dim3(kHeads * kH / 256, kNN / 256, 1), 512, 0, stream>>>(
      xb, W1t, nullptr, h1, nullptr, kNN, kHeads * kH, kH, kH, 0);
  scores_kernel<<<(kNN * kHeads + 3) / 4, 256, 0, stream>>>(h1, att_src1, att_dst1, s1s, s1d,
                                                            kNN * kHeads, kHeads);
  gat_agg_kernel<<<(kNN * kHeads) / 4, 256, 0, stream>>>(rowptr, cols, s1s, s1d, h1, b1, kHeads,
                                                         1, x2, nullptr, kNN * kHeads);

  // GAT layer 2 (1 head): 8-wave engine + split-K (S=4), grid 3x12x4
  gemm8<1><<<dim3(kH / 256, kNN / 256, kSplitK), 512, 0, stream>>>(
      x2, W2t, nullptr, nullptr, part, kNN, kH, kHeads * kH, kHeads * kH / kSplitK, 0);
  splitk_reduce_kernel<<<(kNN * kH / 4 + 255) / 256, 256, 0, stream>>>(
      part, h2, kNN * kH / 4, kSplitK);
  scores_kernel<<<(kNN + 3) / 4, 256, 0, stream>>>(h2, att_src2, att_dst2, s2s, s2d, kNN, 1);
  gat_agg_kernel<<<kNN / 4, 256, 0, stream>>>(rowptr, cols, s2s, s2d, h2, b2, 1, 0, nullptr, xf,
                                              kNN);

  // MLP head
  cat_kernel<<<kB, 256, 0, stream>>>(xf, text_emb, img_emb, user_idx, business_idx, catb);
  mfma_gemm<64, 64, 2, 2, __hip_bfloat16, true><<<dim3(2 * kH / 64, kB / 64), 256, 0, stream>>>(
      catb, Wf1t, bf1, m1, kB, 2 * kH, 4 * kH, 1);
  mfma_gemm<64, 64, 2, 2, float, true><<<dim3(kH / 64, kB / 64), 256, 0, stream>>>(
      m1, Wf2t, bf2, m2, kB, kH, 2 * kH, 1);
  final_kernel<<<(kB * 64 + 255) / 256, 256, 0, stream>>>(m2, Wf3, bf3, out);
}

// Round 6
// 310.687 us; speedup vs baseline: 1.1777x; 1.1777x over previous
//
#include <hip/hip_runtime.h>
#include <hip/hip_bf16.h>

namespace {

constexpr int kB = 1024;      // batch
constexpr int kNU = 1024;     // num users
constexpr int kNB = 2048;     // num businesses
constexpr int kNN = 3072;     // total nodes
constexpr int kE = 16384;     // raw edges
constexpr int kET = kE + kNN; // edges + self loops = 19456
constexpr int kH = 768;
constexpr int kHeads = 8;
constexpr int kSplitK = 4;    // GAT2 split-K factor

typedef __attribute__((ext_vector_type(8))) short bf16x8_t;
typedef __attribute__((ext_vector_type(4))) float f32x4_t;

__device__ __forceinline__ float tof(float x) { return x; }
__device__ __forceinline__ float tof(__hip_bfloat16 x) { return __bfloat162float(x); }
__device__ __forceinline__ void stor(float* p, float v) { *p = v; }
__device__ __forceinline__ void stor(__hip_bfloat16* p, float v) { *p = __float2bfloat16(v); }

__device__ __forceinline__ float blo(unsigned u) {
  union { unsigned u; float f; } c; c.u = u << 16; return c.f;
}
__device__ __forceinline__ float bhi(unsigned u) {
  union { unsigned u; float f; } c; c.u = u & 0xffff0000u; return c.f;
}

__device__ __forceinline__ void gload_lds16(const void* g, void* l) {
  __builtin_amdgcn_global_load_lds(
      (const __attribute__((address_space(1))) void*)g,
      (__attribute__((address_space(3))) void*)l, 16, 0, 0);
}

// ---------------- 2-phase MFMA GEMM (proven r4 engine) ----------------
// A: [M,K] bf16 row-major; Bt: [N,K] bf16 row-major. 4 waves 2x2.
template <int BM, int BN, int FM, int FN, typename TC>
__device__ __forceinline__ void gemm_body(
    const __hip_bfloat16* __restrict__ A, const __hip_bfloat16* __restrict__ Bt,
    const float* __restrict__ bias, TC* __restrict__ C,
    int M, int N, int K, int act, int bx, int by) {
  __shared__ __align__(16) __hip_bfloat16 As[2][BM][32];
  __shared__ __align__(16) __hip_bfloat16 Bs[2][BN][32];
  const int t = threadIdx.x;
  const int w = t >> 6, lane = t & 63;
  const int wm = w >> 1, wn = w & 1;
  const int bm = by * BM, bn = bx * BN;
  const int lr = lane & 15, lg = lane >> 4;

  f32x4_t acc[FM][FN];
#pragma unroll
  for (int m = 0; m < FM; ++m)
#pragma unroll
    for (int n = 0; n < FN; ++n) acc[m][n] = (f32x4_t){0.f, 0.f, 0.f, 0.f};

  auto stage = [&](int buf, int kt) {
    const int k0 = kt << 5;
#pragma unroll
    for (int i = 0; i < BM / 64; ++i) {
      int L = i * 256 + t;
      gload_lds16(A + (size_t)(bm + (L >> 2)) * K + k0 + (L & 3) * 8,
                  (char*)(&As[buf][0][0]) + ((size_t)(i * 256 + w * 64)) * 16);
    }
#pragma unroll
    for (int i = 0; i < BN / 64; ++i) {
      int L = i * 256 + t;
      gload_lds16(Bt + (size_t)(bn + (L >> 2)) * K + k0 + (L & 3) * 8,
                  (char*)(&Bs[buf][0][0]) + ((size_t)(i * 256 + w * 64)) * 16);
    }
  };

  const int NT = K >> 5;
  stage(0, 0);
  __syncthreads();
  for (int kt = 0; kt < NT; ++kt) {
    const int cur = kt & 1;
    if (kt + 1 < NT) stage(cur ^ 1, kt + 1);
    bf16x8_t af[FM], bv[FN];
#pragma unroll
    for (int m = 0; m < FM; ++m)
      af[m] = *(const bf16x8_t*)&As[cur][wm * FM * 16 + m * 16 + lr][lg * 8];
#pragma unroll
    for (int n = 0; n < FN; ++n)
      bv[n] = *(const bf16x8_t*)&Bs[cur][wn * FN * 16 + n * 16 + lr][lg * 8];
#pragma unroll
    for (int m = 0; m < FM; ++m)
#pragma unroll
      for (int n = 0; n < FN; ++n)
        acc[m][n] = __builtin_amdgcn_mfma_f32_16x16x32_bf16(af[m], bv[n], acc[m][n], 0, 0, 0);
    __syncthreads();
  }

#pragma unroll
  for (int m = 0; m < FM; ++m) {
    const int row0 = bm + wm * FM * 16 + m * 16 + lg * 4;
#pragma unroll
    for (int n = 0; n < FN; ++n) {
      const int cn = bn + wn * FN * 16 + n * 16 + lr;
      const float bvv = bias ? bias[cn] : 0.f;
#pragma unroll
      for (int r = 0; r < 4; ++r) {
        float v = acc[m][n][r] + bvv;
        if (act) v = fmaxf(v, 0.f);
        stor(&C[(size_t)(row0 + r) * N + cn], v);
      }
    }
  }
}

__device__ __forceinline__ void swz_xy(bool mfast, int& bx, int& by) {
  const int nwg = gridDim.x * gridDim.y;
  const int orig = blockIdx.y * gridDim.x + blockIdx.x;
  const int swz = (orig & 7) * (nwg >> 3) + (orig >> 3);
  if (mfast) { by = swz % gridDim.y; bx = swz / gridDim.y; }
  else       { bx = swz % gridDim.x; by = swz / gridDim.x; }
}

template <int BM, int BN, int FM, int FN, typename TC, bool MFAST>
__global__ __launch_bounds__(256) void mfma_gemm(
    const __hip_bfloat16* __restrict__ A, const __hip_bfloat16* __restrict__ Bt,
    const float* __restrict__ bias, TC* __restrict__ C,
    int M, int N, int K, int act) {
  int bx, by;
  swz_xy(MFAST, bx, by);
  gemm_body<BM, BN, FM, FN, TC>(A, Bt, bias, C, M, N, K, act, bx, by);
}

template <int BM, int BN, int FM, int FN>
__global__ __launch_bounds__(256) void mfma_gemm_dual(
    const __hip_bfloat16* __restrict__ A0, const __hip_bfloat16* __restrict__ Bt0,
    const float* __restrict__ bias0, float* __restrict__ C0,
    const __hip_bfloat16* __restrict__ A1, const __hip_bfloat16* __restrict__ Bt1,
    const float* __restrict__ bias1, float* __restrict__ C1,
    int M, int N, int K) {
  int bx, by;
  swz_xy(true, bx, by);
  const __hip_bfloat16* A = blockIdx.z ? A1 : A0;
  const __hip_bfloat16* Bt = blockIdx.z ? Bt1 : Bt0;
  const float* bias = blockIdx.z ? bias1 : bias0;
  float* C = blockIdx.z ? C1 : C0;
  gemm_body<BM, BN, FM, FN, float>(A, Bt, bias, C, M, N, K, 0, bx, by);
}

// split-K variant: f32 partials
template <int BM, int BN, int FM, int FN>
__global__ __launch_bounds__(256) void mfma_gemm_splitk(
    const __hip_bfloat16* __restrict__ A, const __hip_bfloat16* __restrict__ Bt,
    float* __restrict__ Cpart, int M, int N, int K, int KC) {
  __shared__ __align__(16) __hip_bfloat16 As[2][BM][32];
  __shared__ __align__(16) __hip_bfloat16 Bs[2][BN][32];
  int bx, by;
  swz_xy(false, bx, by);
  const int t = threadIdx.x;
  const int w = t >> 6, lane = t & 63;
  const int wm = w >> 1, wn = w & 1;
  const int bm = by * BM, bn = bx * BN;
  const int kbeg = blockIdx.z * KC;
  const int lr = lane & 15, lg = lane >> 4;

  f32x4_t acc[FM][FN];
#pragma unroll
  for (int m = 0; m < FM; ++m)
#pragma unroll
    for (int n = 0; n < FN; ++n) acc[m][n] = (f32x4_t){0.f, 0.f, 0.f, 0.f};

  auto stage = [&](int buf, int kt) {
    const int k0 = kbeg + (kt << 5);
#pragma unroll
    for (int i = 0; i < BM / 64; ++i) {
      int L = i * 256 + t;
      gload_lds16(A + (size_t)(bm + (L >> 2)) * K + k0 + (L & 3) * 8,
                  (char*)(&As[buf][0][0]) + ((size_t)(i * 256 + w * 64)) * 16);
    }
#pragma unroll
    for (int i = 0; i < BN / 64; ++i) {
      int L = i * 256 + t;
      gload_lds16(Bt + (size_t)(bn + (L >> 2)) * K + k0 + (L & 3) * 8,
                  (char*)(&Bs[buf][0][0]) + ((size_t)(i * 256 + w * 64)) * 16);
    }
  };

  const int NT = KC >> 5;
  stage(0, 0);
  __syncthreads();
  for (int kt = 0; kt < NT; ++kt) {
    const int cur = kt & 1;
    if (kt + 1 < NT) stage(cur ^ 1, kt + 1);
    bf16x8_t af[FM], bv[FN];
#pragma unroll
    for (int m = 0; m < FM; ++m)
      af[m] = *(const bf16x8_t*)&As[cur][wm * FM * 16 + m * 16 + lr][lg * 8];
#pragma unroll
    for (int n = 0; n < FN; ++n)
      bv[n] = *(const bf16x8_t*)&Bs[cur][wn * FN * 16 + n * 16 + lr][lg * 8];
#pragma unroll
    for (int m = 0; m < FM; ++m)
#pragma unroll
      for (int n = 0; n < FN; ++n)
        acc[m][n] = __builtin_amdgcn_mfma_f32_16x16x32_bf16(af[m], bv[n], acc[m][n], 0, 0, 0);
    __syncthreads();
  }

  float* Cp = Cpart + (size_t)blockIdx.z * M * N;
#pragma unroll
  for (int m = 0; m < FM; ++m) {
    const int row0 = bm + wm * FM * 16 + m * 16 + lg * 4;
#pragma unroll
    for (int n = 0; n < FN; ++n) {
      const int cn = bn + wn * FN * 16 + n * 16 + lr;
#pragma unroll
      for (int r = 0; r < 4; ++r) Cp[(size_t)(row0 + r) * N + cn] = acc[m][n][r];
    }
  }
}

// ---------------- fused split-K reduce + scores2 (one block per row) ----------------
__global__ __launch_bounds__(192) void reduce_scores2_kernel(
    const float* __restrict__ part, const float* __restrict__ att_src,
    const float* __restrict__ att_dst, __hip_bfloat16* __restrict__ h2,
    float* __restrict__ s_src, float* __restrict__ s_dst) {
  __shared__ float redS[3], redD[3];
  const int row = blockIdx.x;
  const int t = threadIdx.x;  // 0..191, owns channels 4t..4t+3
  const int c = t * 4;
  const float* p = part + (size_t)row * kH + c;
  float4 s = *(const float4*)p;
#pragma unroll
  for (int z = 1; z < kSplitK; ++z) {
    float4 qv = *(const float4*)(p + (size_t)z * kNN * kH);
    s.x += qv.x; s.y += qv.y; s.z += qv.z; s.w += qv.w;
  }
  __hip_bfloat16 b0 = __float2bfloat16(s.x), b1 = __float2bfloat16(s.y);
  __hip_bfloat16 b2 = __float2bfloat16(s.z), b3 = __float2bfloat16(s.w);
  __hip_bfloat16* o = h2 + (size_t)row * kH + c;
  o[0] = b0; o[1] = b1; o[2] = b2; o[3] = b3;
  float f0 = tof(b0), f1 = tof(b1), f2 = tof(b2), f3 = tof(b3);
  float ss = f0 * att_src[c] + f1 * att_src[c + 1] + f2 * att_src[c + 2] + f3 * att_src[c + 3];
  float sd = f0 * att_dst[c] + f1 * att_dst[c + 1] + f2 * att_dst[c + 2] + f3 * att_dst[c + 3];
#pragma unroll
  for (int off = 32; off; off >>= 1) { ss += __shfl_down(ss, off); sd += __shfl_down(sd, off); }
  if ((t & 63) == 0) { redS[t >> 6] = ss; redD[t >> 6] = sd; }
  __syncthreads();
  if (t == 0) {
    s_src[row] = redS[0] + redS[1] + redS[2];
    s_dst[row] = redD[0] + redD[1] + redD[2];
  }
}

// ---------------- batched transpose+convert + input prep (one launch) ----------------
struct TJobs {
  const float* in[6];
  __hip_bfloat16* out[6];
  int K[6];
  int N[6];
  int start[7];
};

__global__ __launch_bounds__(256) void transp_prep_kernel(
    TJobs j, const float* __restrict__ text_cls, const float* __restrict__ img_cls,
    __hip_bfloat16* __restrict__ text_bf, __hip_bfloat16* __restrict__ imgm_bf) {
  __shared__ float tl[32][33];
  const int bid = blockIdx.x;
  const int t = threadIdx.x;
  if (bid >= j.start[6]) {
    // input prep region
    int idx = (bid - j.start[6]) * 256 + t;
    if (idx < kB * kH) {
      text_bf[idx] = __float2bfloat16(text_cls[idx]);
      int b = idx / kH, c = idx - b * kH;
      const float* p = img_cls + (size_t)b * 3 * kH + c;
      imgm_bf[idx] = __float2bfloat16((p[0] + p[kH] + p[2 * kH]) * (1.f / 3.f));
    }
    return;
  }
  int idx = 0;
#pragma unroll
  for (int q = 1; q < 6; ++q)
    if (bid >= j.start[q]) idx = q;
  const int tile = bid - j.start[idx];
  const int N = j.N[idx], K = j.K[idx];
  const int tilesN = N >> 5;
  const int n0 = (tile % tilesN) << 5, k0 = (tile / tilesN) << 5;
  const float* in = j.in[idx];
  __hip_bfloat16* out = j.out[idx];
  const int r = t >> 3, c = (t & 7) * 4;
#pragma unroll
  for (int i = 0; i < 4; ++i) tl[r][c + i] = in[(size_t)(k0 + r) * N + n0 + c + i];
  __syncthreads();
  __hip_bfloat16* op = out + (size_t)(n0 + r) * K + k0 + c;
#pragma unroll
  for (int i = 0; i < 4; ++i) op[i] = __float2bfloat16(tl[c + i][r]);
}

// ---------------- workspace init (replaces 3 memsets) ----------------
__global__ void init_kernel(uint4* __restrict__ xb4, int* __restrict__ deg,
                            int* __restrict__ winner) {
  int i = blockIdx.x * 256 + threadIdx.x;
  if (i < kNN * kH * 2 / 16) xb4[i] = (uint4){0u, 0u, 0u, 0u};
  if (i < kNN) deg[i] = 0;
  if (i < kNB) winner[i] = -1;
}

// ---------------- degree count + winner (merged) ----------------
__global__ void deg_winner_kernel(const int* __restrict__ ei, int* __restrict__ deg,
                                  const int* __restrict__ business_idx,
                                  int* __restrict__ winner) {
  int e = blockIdx.x * 256 + threadIdx.x;
  if (e < kET) {
    int dst = (e < kE) ? ei[kE + e] : (e - kE);
    atomicAdd(&deg[dst], 1);
  }
  if (e < kB) atomicMax(&winner[business_idx[e] - kNU], e);
}

__global__ __launch_bounds__(1024) void scan_kernel(const int* __restrict__ deg,
                                                    int* __restrict__ rowptr,
                                                    int* __restrict__ cursor) {
  __shared__ int sums[1024];
  int t = threadIdx.x;
  int v0 = deg[t * 3], v1 = deg[t * 3 + 1], v2 = deg[t * 3 + 2];
  int s = v0 + v1 + v2;
  sums[t] = s;
  __syncthreads();
  for (int o = 1; o < 1024; o <<= 1) {
    int xv = (t >= o) ? sums[t - o] : 0;
    __syncthreads();
    sums[t] += xv;
    __syncthreads();
  }
  int excl = sums[t] - s;
  rowptr[t * 3] = excl;          cursor[t * 3] = excl;
  rowptr[t * 3 + 1] = excl + v0; cursor[t * 3 + 1] = excl + v0;
  rowptr[t * 3 + 2] = excl + v0 + v1; cursor[t * 3 + 2] = excl + v0 + v1;
  if (t == 1023) rowptr[kNN] = excl + s;
}

__global__ void fill_kernel(const int* __restrict__ ei, int* __restrict__ cursor,
                            int* __restrict__ cols) {
  int e = blockIdx.x * 256 + threadIdx.x;
  if (e >= kET) return;
  int src, dst;
  if (e < kE) { src = ei[e]; dst = ei[kE + e]; } else { src = dst = e - kE; }
  int pos = atomicAdd(&cursor[dst], 1);
  cols[pos] = src;
}

// ---------------- node feature build ----------------
__global__ void build_x_kernel(const int* __restrict__ user_idx,
                               const float* __restrict__ user_table,
                               const int* __restrict__ winner,
                               const float* __restrict__ text_emb,
                               const float* __restrict__ img_emb,
                               const float* __restrict__ biz_feats,
                               const float* __restrict__ W_bf,
                               const float* __restrict__ b_bf,
                               const float* __restrict__ biz_table,
                               __hip_bfloat16* __restrict__ xb) {
  int b = blockIdx.x;
  if (b < kNU) {
    int node = user_idx[b];
    for (int c = threadIdx.x; c < kH; c += blockDim.x)
      xb[(size_t)node * kH + c] = __float2bfloat16(user_table[(size_t)node * kH + c]);
  } else {
    int m = b - kNU;
    int w = winner[m];
    if (w < 0) return;
    int node = kNU + m;
    float f0 = biz_feats[w * 3], f1 = biz_feats[w * 3 + 1], f2 = biz_feats[w * 3 + 2];
    for (int c = threadIdx.x; c < kH; c += blockDim.x) {
      float meta = f0 * W_bf[c] + f1 * W_bf[kH + c] + f2 * W_bf[2 * kH + c] + b_bf[c];
      float v = (text_emb[(size_t)w * kH + c] + img_emb[(size_t)w * kH + c] + meta +
                 biz_table[(size_t)m * kH + c]) * 0.25f;
      xb[(size_t)node * kH + c] = __float2bfloat16(v);
    }
  }
}

// ---------------- attention scores (layer 1) ----------------
__global__ __launch_bounds__(256) void scores_kernel(
    const __hip_bfloat16* __restrict__ h, const float* __restrict__ att_src,
    const float* __restrict__ att_dst, float* __restrict__ s_src,
    float* __restrict__ s_dst, int total, int heads) {
  int gw = (blockIdx.x * 256 + threadIdx.x) >> 6;
  int lane = threadIdx.x & 63;
  if (gw >= total) return;
  int hd = gw % heads;
  const unsigned* hp = (const unsigned*)(h + (size_t)gw * kH);
  const float* as = att_src + (size_t)hd * kH;
  const float* ad = att_dst + (size_t)hd * kH;
  float ss = 0.f, sd = 0.f;
  for (int u = lane; u < kH / 2; u += 64) {
    unsigned v = hp[u];
    float f0 = blo(v), f1 = bhi(v);
    int c = u * 2;
    ss = fmaf(f0, as[c], fmaf(f1, as[c + 1], ss));
    sd = fmaf(f0, ad[c], fmaf(f1, ad[c + 1], sd));
  }
#pragma unroll
  for (int o = 32; o; o >>= 1) { ss += __shfl_down(ss, o); sd += __shfl_down(sd, o); }
  if (lane == 0) { s_src[gw] = ss; s_dst[gw] = sd; }
}

// ---------------- GAT segment softmax + aggregation (wave per (node,head)) ----------
// headmaj=1 (heads==8): hd = blockIdx&7 so all blocks of a head land on one XCD
// (round-robin dispatch) -> that XCD's L2 caches just that head's 4.7MB h-slice.
__global__ __launch_bounds__(256) void gat_agg_kernel(
    const int* __restrict__ rowptr, const int* __restrict__ cols,
    const float* __restrict__ s_src, const float* __restrict__ s_dst,
    const __hip_bfloat16* __restrict__ h, const float* __restrict__ bias,
    int heads, int act, __hip_bfloat16* __restrict__ out_bf, float* __restrict__ out_f,
    int total, int headmaj) {
  const int wid = threadIdx.x >> 6;
  const int lane = threadIdx.x & 63;
  int n, hd, pair;
  if (headmaj) {
    hd = blockIdx.x & 7;
    n = (blockIdx.x >> 3) * 4 + wid;
    pair = n * heads + hd;
  } else {
    pair = blockIdx.x * 4 + wid;
    n = pair / heads;
    hd = pair - n * heads;
  }
  if (pair >= total || n >= kNN) return;
  const int beg = rowptr[n], end = rowptr[n + 1];
  const float sdv = s_dst[pair];

  float m = -3.402823466e38f;
  for (int i = beg + lane; i < end; i += 64) {
    float e = s_src[(size_t)cols[i] * heads + hd] + sdv;
    e = (e > 0.f) ? e : 0.2f * e;
    m = fmaxf(m, e);
  }
#pragma unroll
  for (int o = 32; o; o >>= 1) m = fmaxf(m, __shfl_xor(m, o));

  float dsum = 0.f;
  for (int i = beg + lane; i < end; i += 64) {
    float e = s_src[(size_t)cols[i] * heads + hd] + sdv;
    e = (e > 0.f) ? e : 0.2f * e;
    dsum += expf(e - m);
  }
#pragma unroll
  for (int o = 32; o; o >>= 1) dsum += __shfl_xor(dsum, o);
  const float rdsum = 1.f / (dsum + 1e-16f);

  float a[12];
#pragma unroll
  for (int q = 0; q < 12; ++q) a[q] = 0.f;
  const size_t hs = (size_t)heads * kH;
  const size_t hoff = (size_t)hd * kH + (size_t)lane * 4;
  for (int i = beg; i < end; ++i) {
    int src = cols[i];
    float e = s_src[(size_t)src * heads + hd] + sdv;
    e = (e > 0.f) ? e : 0.2f * e;
    float wgt = expf(e - m) * rdsum;
    const __hip_bfloat16* hp = h + (size_t)src * hs + hoff;
#pragma unroll
    for (int j = 0; j < 3; ++j) {
      uint2 v = *(const uint2*)(hp + j * 256);
      a[j * 4 + 0] = fmaf(wgt, blo(v.x), a[j * 4 + 0]);
      a[j * 4 + 1] = fmaf(wgt, bhi(v.x), a[j * 4 + 1]);
      a[j * 4 + 2] = fmaf(wgt, blo(v.y), a[j * 4 + 2]);
      a[j * 4 + 3] = fmaf(wgt, bhi(v.y), a[j * 4 + 3]);
    }
  }
  const size_t ob = (size_t)n * hs + hoff;
  const size_t bb = (size_t)hd * kH + (size_t)lane * 4;
#pragma unroll
  for (int j = 0; j < 3; ++j) {
#pragma unroll
    for (int q = 0; q < 4; ++q) {
      float v = a[j * 4 + q] + bias[bb + j * 256 + q];
      if (act) v = fmaxf(v, 0.f);
      if (out_bf) out_bf[ob + j * 256 + q] = __float2bfloat16(v);
      else out_f[ob + j * 256 + q] = v;
    }
  }
}

// ---------------- MLP head ----------------
__global__ void cat_kernel(const float* __restrict__ xf, const float* __restrict__ text_emb,
                           const float* __restrict__ img_emb, const int* __restrict__ user_idx,
                           const int* __restrict__ business_idx, __hip_bfloat16* __restrict__ cat) {
  int b = blockIdx.x;
  int u = user_idx[b], z = business_idx[b];
  __hip_bfloat16* crow = cat + (size_t)b * 4 * kH;
  for (int c = threadIdx.x; c < kH; c += blockDim.x) {
    crow[c] = __float2bfloat16(xf[(size_t)u * kH + c]);
    crow[kH + c] = __float2bfloat16(xf[(size_t)z * kH + c]);
    crow[2 * kH + c] = __float2bfloat16(text_emb[(size_t)b * kH + c]);
    crow[3 * kH + c] = __float2bfloat16(img_emb[(size_t)b * kH + c]);
  }
}

__global__ __launch_bounds__(256) void final_kernel(const float* __restrict__ m2,
                                                    const float* __restrict__ Wf3,
                                                    const float* __restrict__ bf3,
                                                    float* __restrict__ out) {
  int b = (blockIdx.x * 256 + threadIdx.x) >> 6;
  int lane = threadIdx.x & 63;
  if (b >= kB) return;
  float s = 0.f;
  for (int c = lane; c < kH; c += 64) s = fmaf(m2[(size_t)b * kH + c], Wf3[c], s);
#pragma unroll
  for (int o = 32; o; o >>= 1) s += __shfl_down(s, o);
  if (lane == 0) out[b] = s + bf3[0];
}

}  // namespace

extern "C" void kernel_launch(void* const* d_in, const int* in_sizes, int n_in,
                              void* d_out, int out_size, void* d_ws, size_t ws_size,
                              hipStream_t stream) {
  const float* text_cls = (const float*)d_in[0];
  const float* img_cls = (const float*)d_in[1];
  const float* biz_feats = (const float*)d_in[2];
  const float* W_text = (const float*)d_in[3];
  const float* b_text = (const float*)d_in[4];
  const float* W_img = (const float*)d_in[5];
  const float* b_img = (const float*)d_in[6];
  const float* W_bf = (const float*)d_in[7];
  const float* b_bf = (const float*)d_in[8];
  const float* user_table = (const float*)d_in[9];
  const float* biz_table = (const float*)d_in[10];
  const float* W1 = (const float*)d_in[11];
  const float* att_src1 = (const float*)d_in[12];
  const float* att_dst1 = (const float*)d_in[13];
  const float* b1 = (const float*)d_in[14];
  const float* W2 = (const float*)d_in[15];
  const float* att_src2 = (const float*)d_in[16];
  const float* att_dst2 = (const float*)d_in[17];
  const float* b2 = (const float*)d_in[18];
  const float* Wf1 = (const float*)d_in[19];
  const float* bf1 = (const float*)d_in[20];
  const float* Wf2 = (const float*)d_in[21];
  const float* bf2 = (const float*)d_in[22];
  const float* Wf3 = (const float*)d_in[23];
  const float* bf3 = (const float*)d_in[24];
  const int* user_idx = (const int*)d_in[25];
  const int* business_idx = (const int*)d_in[26];
  const int* edge_index = (const int*)d_in[27];
  float* out = (float*)d_out;
  (void)in_sizes; (void)n_in; (void)out_size; (void)ws_size;

  char* base = (char*)d_ws;
  size_t off = 0;
  auto alloc = [&](size_t bytes) -> void* {
    void* p = base + off;
    off = (off + bytes + 255) & ~(size_t)255;
    return p;
  };
  __hip_bfloat16* xb = (__hip_bfloat16*)alloc((size_t)kNN * kH * 2);
  __hip_bfloat16* text_bf = (__hip_bfloat16*)alloc((size_t)kB * kH * 2);
  __hip_bfloat16* imgm_bf = (__hip_bfloat16*)alloc((size_t)kB * kH * 2);
  float* text_emb = (float*)alloc((size_t)kB * kH * 4);
  float* img_emb = (float*)alloc((size_t)kB * kH * 4);
  __hip_bfloat16* Wtt = (__hip_bfloat16*)alloc((size_t)kH * kH * 2);
  __hip_bfloat16* Wit = (__hip_bfloat16*)alloc((size_t)kH * kH * 2);
  __hip_bfloat16* W1t = (__hip_bfloat16*)alloc((size_t)kHeads * kH * kH * 2);
  __hip_bfloat16* W2t = (__hip_bfloat16*)alloc((size_t)kH * kHeads * kH * 2);
  __hip_bfloat16* Wf1t = (__hip_bfloat16*)alloc((size_t)2 * kH * 4 * kH * 2);
  __hip_bfloat16* Wf2t = (__hip_bfloat16*)alloc((size_t)kH * 2 * kH * 2);
  __hip_bfloat16* h1 = (__hip_bfloat16*)alloc((size_t)kNN * kHeads * kH * 2);
  __hip_bfloat16* x2 = (__hip_bfloat16*)alloc((size_t)kNN * kHeads * kH * 2);
  __hip_bfloat16* h2 = (__hip_bfloat16*)alloc((size_t)kNN * kH * 2);
  float* xf = (float*)alloc((size_t)kNN * kH * 4);
  float* s1s = (float*)alloc((size_t)kNN * kHeads * 4);
  float* s1d = (float*)alloc((size_t)kNN * kHeads * 4);
  float* s2s = (float*)alloc((size_t)kNN * 4);
  float* s2d = (float*)alloc((size_t)kNN * 4);
  __hip_bfloat16* catb = (__hip_bfloat16*)alloc((size_t)kB * 4 * kH * 2);
  __hip_bfloat16* m1 = (__hip_bfloat16*)alloc((size_t)kB * 2 * kH * 2);
  float* m2 = (float*)alloc((size_t)kB * kH * 4);
  int* deg = (int*)alloc((size_t)kNN * 4);
  int* rowptr = (int*)alloc((size_t)(kNN + 1) * 4);
  int* cursor = (int*)alloc((size_t)kNN * 4);
  int* cols = (int*)alloc((size_t)kET * 4);
  int* winner = (int*)alloc((size_t)kNB * 4);

  // split-K partials aliased over h1 (dead after scores1/agg1): exact fit for S=4
  float* part = (float*)h1;

  // init (replaces 3 memsets): zero xb, deg; winner = -1
  init_kernel<<<(kNN * kH * 2 / 16 + 255) / 256, 256, 0, stream>>>((uint4*)xb, deg, winner);

  // batched weight transposes + input prep in one launch
  TJobs tj;
  tj.in[0] = W_text; tj.out[0] = Wtt;  tj.K[0] = kH;          tj.N[0] = kH;
  tj.in[1] = W_img;  tj.out[1] = Wit;  tj.K[1] = kH;          tj.N[1] = kH;
  tj.in[2] = W1;     tj.out[2] = W1t;  tj.K[2] = kH;          tj.N[2] = kHeads * kH;
  tj.in[3] = W2;     tj.out[3] = W2t;  tj.K[3] = kHeads * kH; tj.N[3] = kH;
  tj.in[4] = Wf1;    tj.out[4] = Wf1t; tj.K[4] = 4 * kH;      tj.N[4] = 2 * kH;
  tj.in[5] = Wf2;    tj.out[5] = Wf2t; tj.K[5] = 2 * kH;      tj.N[5] = kH;
  tj.start[0] = 0;
  for (int q = 0; q < 6; ++q)
    tj.start[q + 1] = tj.start[q] + (tj.K[q] / 32) * (tj.N[q] / 32);
  const int prep_blocks = (kB * kH + 255) / 256;
  transp_prep_kernel<<<tj.start[6] + prep_blocks, 256, 0, stream>>>(tj, text_cls, img_cls,
                                                                    text_bf, imgm_bf);

  // encoders, batched in z
  mfma_gemm_dual<64, 64, 2, 2><<<dim3(kH / 64, kB / 64, 2), 256, 0, stream>>>(
      text_bf, Wtt, b_text, text_emb, imgm_bf, Wit, b_img, img_emb, kB, kH, kH);

  // CSR degree + winner
  deg_winner_kernel<<<(kET + 255) / 256, 256, 0, stream>>>(edge_index, deg, business_idx, winner);
  scan_kernel<<<1, 1024, 0, stream>>>(deg, rowptr, cursor);
  fill_kernel<<<(kET + 255) / 256, 256, 0, stream>>>(edge_index, cursor, cols);

  // node features
  build_x_kernel<<<kNN, 256, 0, stream>>>(user_idx, user_table, winner, text_emb, img_emb,
                                          biz_feats, W_bf, b_bf, biz_table, xb);

  // GAT layer 1 (8 heads): proven 2-phase 128^2, grid 48x24, M-fast swizzle
  mfma_gemm<128, 128, 4, 4, __hip_bfloat16, true>
      <<<dim3(kHeads * kH / 128, kNN / 128), 256, 0, stream>>>(
          xb, W1t, nullptr, h1, kNN, kHeads * kH, kH, 0);
  scores_kernel<<<(kNN * kHeads + 3) / 4, 256, 0, stream>>>(h1, att_src1, att_dst1, s1s, s1d,
                                                            kNN * kHeads, kHeads);
  // head-major block mapping: head = blockIdx & 7 -> per-XCD L2 head-slice locality
  gat_agg_kernel<<<kHeads * (kNN / 4), 256, 0, stream>>>(rowptr, cols, s1s, s1d, h1, b1, kHeads,
                                                         1, x2, nullptr, kNN * kHeads, 1);

  // GAT layer 2 (1 head): split-K (proven r4 config), then fused reduce+scores2
  mfma_gemm_splitk<64, 128, 2, 4><<<dim3(kH / 128, kNN / 64, kSplitK), 256, 0, stream>>>(
      x2, W2t, part, kNN, kH, kHeads * kH, kHeads * kH / kSplitK);
  reduce_scores2_kernel<<<kNN, 192, 0, stream>>>(part, att_src2, att_dst2, h2, s2s, s2d);
  gat_agg_kernel<<<kNN / 4, 256, 0, stream>>>(rowptr, cols, s2s, s2d, h2, b2, 1, 0, nullptr, xf,
                                              kNN, 0);

  // MLP head
  cat_kernel<<<kB, 256, 0, stream>>>(xf, text_emb, img_emb, user_idx, business_idx, catb);
  mfma_gemm<64, 64, 2, 2, __hip_bfloat16, true><<<dim3(2 * kH / 64, kB / 64), 256, 0, stream>>>(
      catb, Wf1t, bf1, m1, kB, 2 * kH, 4 * kH, 1);
  mfma_gemm<64, 64, 2, 2, float, true><<<dim3(kH / 64, kB / 64), 256, 0, stream>>>(
      m1, Wf2t, bf2, m2, kB, kH, 2 * kH, 1);
  final_kernel<<<(kB * 64 + 255) / 256, 256, 0, stream>>>(m2, Wf3, bf3, out);
}

// Round 7
// 305.656 us; speedup vs baseline: 1.1970x; 1.0165x over previous
//
#include <hip/hip_runtime.h>
#include <hip/hip_bf16.h>

namespace {

constexpr int kB = 1024;      // batch
constexpr int kNU = 1024;     // num users
constexpr int kNB = 2048;     // num businesses
constexpr int kNN = 3072;     // total nodes
constexpr int kE = 16384;     // raw edges
constexpr int kET = kE + kNN; // edges + self loops = 19456
constexpr int kH = 768;
constexpr int kHeads = 8;
constexpr int kSplitK = 4;    // GAT2 split-K factor

typedef __attribute__((ext_vector_type(8))) short bf16x8_t;
typedef __attribute__((ext_vector_type(4))) float f32x4_t;

__device__ __forceinline__ float tof(float x) { return x; }
__device__ __forceinline__ float tof(__hip_bfloat16 x) { return __bfloat162float(x); }
__device__ __forceinline__ void stor(float* p, float v) { *p = v; }
__device__ __forceinline__ void stor(__hip_bfloat16* p, float v) { *p = __float2bfloat16(v); }

__device__ __forceinline__ float blo(unsigned u) {
  union { unsigned u; float f; } c; c.u = u << 16; return c.f;
}
__device__ __forceinline__ float bhi(unsigned u) {
  union { unsigned u; float f; } c; c.u = u & 0xffff0000u; return c.f;
}

__device__ __forceinline__ unsigned pk2(float a, float b) {
  union { __hip_bfloat16 h[2]; unsigned u; } c;
  c.h[0] = __float2bfloat16(a); c.h[1] = __float2bfloat16(b);
  return c.u;
}

__device__ __forceinline__ void gload_lds16(const void* g, void* l) {
  __builtin_amdgcn_global_load_lds(
      (const __attribute__((address_space(1))) void*)g,
      (__attribute__((address_space(3))) void*)l, 16, 0, 0);
}

// ---------------- 2-phase MFMA GEMM (proven engine), now with lda/ldc ----------------
// A: [M,K] bf16, row stride lda; Bt: [N,K] bf16 row-major (stride K). 4 waves 2x2.
template <int BM, int BN, int FM, int FN, typename TC>
__device__ __forceinline__ void gemm_body(
    const __hip_bfloat16* __restrict__ A, const __hip_bfloat16* __restrict__ Bt,
    const float* __restrict__ bias, TC* __restrict__ C,
    int K, int lda, int ldc, int act, int bx, int by) {
  __shared__ __align__(16) __hip_bfloat16 As[2][BM][32];
  __shared__ __align__(16) __hip_bfloat16 Bs[2][BN][32];
  const int t = threadIdx.x;
  const int w = t >> 6, lane = t & 63;
  const int wm = w >> 1, wn = w & 1;
  const int bm = by * BM, bn = bx * BN;
  const int lr = lane & 15, lg = lane >> 4;

  f32x4_t acc[FM][FN];
#pragma unroll
  for (int m = 0; m < FM; ++m)
#pragma unroll
    for (int n = 0; n < FN; ++n) acc[m][n] = (f32x4_t){0.f, 0.f, 0.f, 0.f};

  auto stage = [&](int buf, int kt) {
    const int k0 = kt << 5;
#pragma unroll
    for (int i = 0; i < BM / 64; ++i) {
      int L = i * 256 + t;
      gload_lds16(A + (size_t)(bm + (L >> 2)) * lda + k0 + (L & 3) * 8,
                  (char*)(&As[buf][0][0]) + ((size_t)(i * 256 + w * 64)) * 16);
    }
#pragma unroll
    for (int i = 0; i < BN / 64; ++i) {
      int L = i * 256 + t;
      gload_lds16(Bt + (size_t)(bn + (L >> 2)) * K + k0 + (L & 3) * 8,
                  (char*)(&Bs[buf][0][0]) + ((size_t)(i * 256 + w * 64)) * 16);
    }
  };

  const int NT = K >> 5;
  stage(0, 0);
  __syncthreads();
  for (int kt = 0; kt < NT; ++kt) {
    const int cur = kt & 1;
    if (kt + 1 < NT) stage(cur ^ 1, kt + 1);
    bf16x8_t af[FM], bv[FN];
#pragma unroll
    for (int m = 0; m < FM; ++m)
      af[m] = *(const bf16x8_t*)&As[cur][wm * FM * 16 + m * 16 + lr][lg * 8];
#pragma unroll
    for (int n = 0; n < FN; ++n)
      bv[n] = *(const bf16x8_t*)&Bs[cur][wn * FN * 16 + n * 16 + lr][lg * 8];
#pragma unroll
    for (int m = 0; m < FM; ++m)
#pragma unroll
      for (int n = 0; n < FN; ++n)
        acc[m][n] = __builtin_amdgcn_mfma_f32_16x16x32_bf16(af[m], bv[n], acc[m][n], 0, 0, 0);
    __syncthreads();
  }

#pragma unroll
  for (int m = 0; m < FM; ++m) {
    const int row0 = bm + wm * FM * 16 + m * 16 + lg * 4;
#pragma unroll
    for (int n = 0; n < FN; ++n) {
      const int cn = bn + wn * FN * 16 + n * 16 + lr;
      const float bvv = bias ? bias[cn] : 0.f;
#pragma unroll
      for (int r = 0; r < 4; ++r) {
        float v = acc[m][n][r] + bvv;
        if (act) v = fmaxf(v, 0.f);
        stor(&C[(size_t)(row0 + r) * ldc + cn], v);
      }
    }
  }
}

__device__ __forceinline__ void swz_xy(bool mfast, int& bx, int& by) {
  const int nwg = gridDim.x * gridDim.y;
  const int orig = blockIdx.y * gridDim.x + blockIdx.x;
  const int swz = (orig & 7) * (nwg >> 3) + (orig >> 3);
  if (mfast) { by = swz % gridDim.y; bx = swz / gridDim.y; }
  else       { bx = swz % gridDim.x; by = swz / gridDim.x; }
}

template <int BM, int BN, int FM, int FN, typename TC, bool MFAST>
__global__ __launch_bounds__(256) void mfma_gemm(
    const __hip_bfloat16* __restrict__ A, const __hip_bfloat16* __restrict__ Bt,
    const float* __restrict__ bias, TC* __restrict__ C,
    int N, int K, int act) {
  int bx, by;
  swz_xy(MFAST, bx, by);
  gemm_body<BM, BN, FM, FN, TC>(A, Bt, bias, C, K, K, N, act, bx, by);
}

template <int BM, int BN, int FM, int FN>
__global__ __launch_bounds__(256) void mfma_gemm_dual(
    const __hip_bfloat16* __restrict__ A0, const __hip_bfloat16* __restrict__ Bt0,
    const float* __restrict__ bias0, float* __restrict__ C0,
    const __hip_bfloat16* __restrict__ A1, const __hip_bfloat16* __restrict__ Bt1,
    const float* __restrict__ bias1, float* __restrict__ C1,
    int N, int K) {
  int bx, by;
  swz_xy(true, bx, by);
  const __hip_bfloat16* A = blockIdx.z ? A1 : A0;
  const __hip_bfloat16* Bt = blockIdx.z ? Bt1 : Bt0;
  const float* bias = blockIdx.z ? bias1 : bias0;
  float* C = blockIdx.z ? C1 : C0;
  gemm_body<BM, BN, FM, FN, float>(A, Bt, bias, C, K, K, N, 0, bx, by);
}

// per-head batched projection: x2[:, hd*768:+768] = relu(Y_hd @ W1_hd^T + b1_hd)
template <int BM, int BN, int FM, int FN>
__global__ __launch_bounds__(256) void gemm_head(
    const __hip_bfloat16* __restrict__ y, const __hip_bfloat16* __restrict__ W1t,
    const float* __restrict__ b1, __hip_bfloat16* __restrict__ x2) {
  int bx, by;
  swz_xy(true, bx, by);
  const int hd = blockIdx.z;
  gemm_body<BM, BN, FM, FN, __hip_bfloat16>(
      y + (size_t)hd * kH, W1t + (size_t)hd * kH * kH, b1 + hd * kH,
      x2 + (size_t)hd * kH, kH, kHeads * kH, kHeads * kH, 1, bx, by);
}

// split-K variant: f32 partials (unchanged proven r4 kernel)
template <int BM, int BN, int FM, int FN>
__global__ __launch_bounds__(256) void mfma_gemm_splitk(
    const __hip_bfloat16* __restrict__ A, const __hip_bfloat16* __restrict__ Bt,
    float* __restrict__ Cpart, int M, int N, int K, int KC) {
  __shared__ __align__(16) __hip_bfloat16 As[2][BM][32];
  __shared__ __align__(16) __hip_bfloat16 Bs[2][BN][32];
  int bx, by;
  swz_xy(false, bx, by);
  const int t = threadIdx.x;
  const int w = t >> 6, lane = t & 63;
  const int wm = w >> 1, wn = w & 1;
  const int bm = by * BM, bn = bx * BN;
  const int kbeg = blockIdx.z * KC;
  const int lr = lane & 15, lg = lane >> 4;

  f32x4_t acc[FM][FN];
#pragma unroll
  for (int m = 0; m < FM; ++m)
#pragma unroll
    for (int n = 0; n < FN; ++n) acc[m][n] = (f32x4_t){0.f, 0.f, 0.f, 0.f};

  auto stage = [&](int buf, int kt) {
    const int k0 = kbeg + (kt << 5);
#pragma unroll
    for (int i = 0; i < BM / 64; ++i) {
      int L = i * 256 + t;
      gload_lds16(A + (size_t)(bm + (L >> 2)) * K + k0 + (L & 3) * 8,
                  (char*)(&As[buf][0][0]) + ((size_t)(i * 256 + w * 64)) * 16);
    }
#pragma unroll
    for (int i = 0; i < BN / 64; ++i) {
      int L = i * 256 + t;
      gload_lds16(Bt + (size_t)(bn + (L >> 2)) * K + k0 + (L & 3) * 8,
                  (char*)(&Bs[buf][0][0]) + ((size_t)(i * 256 + w * 64)) * 16);
    }
  };

  const int NT = KC >> 5;
  stage(0, 0);
  __syncthreads();
  for (int kt = 0; kt < NT; ++kt) {
    const int cur = kt & 1;
    if (kt + 1 < NT) stage(cur ^ 1, kt + 1);
    bf16x8_t af[FM], bv[FN];
#pragma unroll
    for (int m = 0; m < FM; ++m)
      af[m] = *(const bf16x8_t*)&As[cur][wm * FM * 16 + m * 16 + lr][lg * 8];
#pragma unroll
    for (int n = 0; n < FN; ++n)
      bv[n] = *(const bf16x8_t*)&Bs[cur][wn * FN * 16 + n * 16 + lr][lg * 8];
#pragma unroll
    for (int m = 0; m < FM; ++m)
#pragma unroll
      for (int n = 0; n < FN; ++n)
        acc[m][n] = __builtin_amdgcn_mfma_f32_16x16x32_bf16(af[m], bv[n], acc[m][n], 0, 0, 0);
    __syncthreads();
  }

  float* Cp = Cpart + (size_t)blockIdx.z * M * N;
#pragma unroll
  for (int m = 0; m < FM; ++m) {
    const int row0 = bm + wm * FM * 16 + m * 16 + lg * 4;
#pragma unroll
    for (int n = 0; n < FN; ++n) {
      const int cn = bn + wn * FN * 16 + n * 16 + lr;
#pragma unroll
      for (int r = 0; r < 4; ++r) Cp[(size_t)(row0 + r) * N + cn] = acc[m][n][r];
    }
  }
}

// ---------------- fused split-K reduce + scores2 (one block per row) ----------------
__global__ __launch_bounds__(192) void reduce_scores2_kernel(
    const float* __restrict__ part, const float* __restrict__ att_src,
    const float* __restrict__ att_dst, __hip_bfloat16* __restrict__ h2,
    float* __restrict__ s_src, float* __restrict__ s_dst) {
  __shared__ float redS[3], redD[3];
  const int row = blockIdx.x;
  const int t = threadIdx.x;  // 0..191, owns channels 4t..4t+3
  const int c = t * 4;
  const float* p = part + (size_t)row * kH + c;
  float4 s = *(const float4*)p;
#pragma unroll
  for (int z = 1; z < kSplitK; ++z) {
    float4 qv = *(const float4*)(p + (size_t)z * kNN * kH);
    s.x += qv.x; s.y += qv.y; s.z += qv.z; s.w += qv.w;
  }
  __hip_bfloat16 b0 = __float2bfloat16(s.x), b1 = __float2bfloat16(s.y);
  __hip_bfloat16 b2 = __float2bfloat16(s.z), b3 = __float2bfloat16(s.w);
  __hip_bfloat16* o = h2 + (size_t)row * kH + c;
  o[0] = b0; o[1] = b1; o[2] = b2; o[3] = b3;
  float f0 = tof(b0), f1 = tof(b1), f2 = tof(b2), f3 = tof(b3);
  float ss = f0 * att_src[c] + f1 * att_src[c + 1] + f2 * att_src[c + 2] + f3 * att_src[c + 3];
  float sd = f0 * att_dst[c] + f1 * att_dst[c + 1] + f2 * att_dst[c + 2] + f3 * att_dst[c + 3];
#pragma unroll
  for (int off = 32; off; off >>= 1) { ss += __shfl_down(ss, off); sd += __shfl_down(sd, off); }
  if ((t & 63) == 0) { redS[t >> 6] = ss; redD[t >> 6] = sd; }
  __syncthreads();
  if (t == 0) {
    s_src[row] = redS[0] + redS[1] + redS[2];
    s_dst[row] = redD[0] + redD[1] + redD[2];
  }
}

// ---------------- batched transpose+convert + input prep (one launch) ----------------
struct TJobs {
  const float* in[6];
  __hip_bfloat16* out[6];
  int K[6];
  int N[6];
  int start[7];
};

__global__ __launch_bounds__(256) void transp_prep_kernel(
    TJobs j, const float* __restrict__ text_cls, const float* __restrict__ img_cls,
    __hip_bfloat16* __restrict__ text_bf, __hip_bfloat16* __restrict__ imgm_bf) {
  __shared__ float tl[32][33];
  const int bid = blockIdx.x;
  const int t = threadIdx.x;
  if (bid >= j.start[6]) {
    int idx = (bid - j.start[6]) * 256 + t;
    if (idx < kB * kH) {
      text_bf[idx] = __float2bfloat16(text_cls[idx]);
      int b = idx / kH, c = idx - b * kH;
      const float* p = img_cls + (size_t)b * 3 * kH + c;
      imgm_bf[idx] = __float2bfloat16((p[0] + p[kH] + p[2 * kH]) * (1.f / 3.f));
    }
    return;
  }
  int idx = 0;
#pragma unroll
  for (int q = 1; q < 6; ++q)
    if (bid >= j.start[q]) idx = q;
  const int tile = bid - j.start[idx];
  const int N = j.N[idx], K = j.K[idx];
  const int tilesN = N >> 5;
  const int n0 = (tile % tilesN) << 5, k0 = (tile / tilesN) << 5;
  const float* in = j.in[idx];
  __hip_bfloat16* out = j.out[idx];
  const int r = t >> 3, c = (t & 7) * 4;
#pragma unroll
  for (int i = 0; i < 4; ++i) tl[r][c + i] = in[(size_t)(k0 + r) * N + n0 + c + i];
  __syncthreads();
  __hip_bfloat16* op = out + (size_t)(n0 + r) * K + k0 + c;
#pragma unroll
  for (int i = 0; i < 4; ++i) op[i] = __float2bfloat16(tl[c + i][r]);
}

// ---------------- wa1: per-head projected attention vectors ----------------
// wa[0][hd][i] = sum_c W1[i][hd*768+c]*a_src[hd][c]; wa[1][..] with a_dst
__global__ __launch_bounds__(256) void wa1_kernel(const float* __restrict__ W1,
                                                  const float* __restrict__ a_src,
                                                  const float* __restrict__ a_dst,
                                                  float* __restrict__ wa) {
  int gw = (blockIdx.x * 256 + threadIdx.x) >> 6;
  int lane = threadIdx.x & 63;
  if (gw >= kHeads * kH) return;
  int i = gw >> 3, hd = gw & 7;
  const float* wrow = W1 + (size_t)i * (kHeads * kH) + hd * kH;
  const float* as = a_src + (size_t)hd * kH;
  const float* ad = a_dst + (size_t)hd * kH;
  float ss = 0.f, sd = 0.f;
  for (int c = lane; c < kH; c += 64) {
    float wv = wrow[c];
    ss = fmaf(wv, as[c], ss);
    sd = fmaf(wv, ad[c], sd);
  }
#pragma unroll
  for (int o = 32; o; o >>= 1) { ss += __shfl_down(ss, o); sd += __shfl_down(sd, o); }
  if (lane == 0) {
    wa[hd * kH + i] = ss;
    wa[kHeads * kH + hd * kH + i] = sd;
  }
}

// ---------------- s1: scores from x (768-dim) ----------------
// s1s[n*8+hd] = x[n] . wa[0][hd];  s1d likewise. Block per node, wave w -> heads w, w+4.
__global__ __launch_bounds__(256) void s1_kernel(const __hip_bfloat16* __restrict__ xb,
                                                 const float* __restrict__ wa,
                                                 float* __restrict__ s1s,
                                                 float* __restrict__ s1d) {
  __shared__ unsigned xrow[kH / 2];
  const int n = blockIdx.x;
  const int t = threadIdx.x;
  const unsigned* xp = (const unsigned*)(xb + (size_t)n * kH);
  if (t < 128) { xrow[t] = xp[t]; xrow[t + 128] = xp[t + 128]; xrow[t + 256] = xp[t + 256]; }
  __syncthreads();
  const int w = t >> 6, lane = t & 63;
  const float* ws0 = wa + (size_t)w * kH;
  const float* wd0 = wa + (size_t)(kHeads + w) * kH;
  const float* ws1 = wa + (size_t)(w + 4) * kH;
  const float* wd1 = wa + (size_t)(kHeads + w + 4) * kH;
  float s0 = 0.f, d0 = 0.f, s1 = 0.f, d1 = 0.f;
  for (int u = lane; u < kH / 2; u += 64) {
    unsigned v = xrow[u];
    float f0 = blo(v), f1 = bhi(v);
    int c = u * 2;
    s0 = fmaf(f0, ws0[c], fmaf(f1, ws0[c + 1], s0));
    d0 = fmaf(f0, wd0[c], fmaf(f1, wd0[c + 1], d0));
    s1 = fmaf(f0, ws1[c], fmaf(f1, ws1[c + 1], s1));
    d1 = fmaf(f0, wd1[c], fmaf(f1, wd1[c + 1], d1));
  }
#pragma unroll
  for (int o = 32; o; o >>= 1) {
    s0 += __shfl_down(s0, o); d0 += __shfl_down(d0, o);
    s1 += __shfl_down(s1, o); d1 += __shfl_down(d1, o);
  }
  if (lane == 0) {
    s1s[n * 8 + w] = s0;     s1d[n * 8 + w] = d0;
    s1s[n * 8 + w + 4] = s1; s1d[n * 8 + w + 4] = d1;
  }
}

// ---------------- layer-1 aggregation in x-space ----------------
// y[n][hd][c] = sum_e alpha_e^hd * x[src_e][c]   (768-dim gather shared by 8 heads)
__global__ __launch_bounds__(256) void agg1x_kernel(
    const int* __restrict__ rowptr, const int* __restrict__ cols,
    const float* __restrict__ s1s, const float* __restrict__ s1d,
    const __hip_bfloat16* __restrict__ xb, __hip_bfloat16* __restrict__ y) {
  __shared__ float mh[8], rdh[8], sdl[8];
  __shared__ float alph[128][9];
  const int n = blockIdx.x;
  const int t = threadIdx.x, w = t >> 6, lane = t & 63;
  const int beg = rowptr[n], end = rowptr[n + 1];
  if (t < 8) sdl[t] = s1d[n * 8 + t];
  __syncthreads();
  // per-wave: heads w and w+4 -> max and denom
#pragma unroll
  for (int p = 0; p < 2; ++p) {
    const int h = w + p * 4;
    const float sd = sdl[h];
    float m = -3.402823466e38f;
    for (int i = beg + lane; i < end; i += 64) {
      float e = s1s[(size_t)cols[i] * 8 + h] + sd;
      e = (e > 0.f) ? e : 0.2f * e;
      m = fmaxf(m, e);
    }
#pragma unroll
    for (int o = 32; o; o >>= 1) m = fmaxf(m, __shfl_xor(m, o));
    float ds = 0.f;
    for (int i = beg + lane; i < end; i += 64) {
      float e = s1s[(size_t)cols[i] * 8 + h] + sd;
      e = (e > 0.f) ? e : 0.2f * e;
      ds += expf(e - m);
    }
#pragma unroll
    for (int o = 32; o; o >>= 1) ds += __shfl_xor(ds, o);
    if (lane == 0) { mh[h] = m; rdh[h] = 1.f / (ds + 1e-16f); }
  }
  __syncthreads();

  float acc[8][4];
#pragma unroll
  for (int h = 0; h < 8; ++h)
#pragma unroll
    for (int q = 0; q < 4; ++q) acc[h][q] = 0.f;
  const int c0 = t * 4;  // threads 0..191 own channels 4t..4t+3

  for (int chunk = beg; chunk < end; chunk += 128) {
    const int cnt = min(128, end - chunk);
#pragma unroll
    for (int p = 0; p < 2; ++p) {
      const int h = w + p * 4;
      const float sd = sdl[h], m = mh[h], rd = rdh[h];
      for (int i = lane; i < cnt; i += 64) {
        float e = s1s[(size_t)cols[chunk + i] * 8 + h] + sd;
        e = (e > 0.f) ? e : 0.2f * e;
        alph[i][h] = expf(e - m) * rd;
      }
    }
    __syncthreads();
    if (t < 192) {
      for (int i = 0; i < cnt; ++i) {
        int src = cols[chunk + i];
        uint2 v = *(const uint2*)(xb + (size_t)src * kH + c0);
        float f0 = blo(v.x), f1 = bhi(v.x), f2 = blo(v.y), f3 = bhi(v.y);
#pragma unroll
        for (int h = 0; h < 8; ++h) {
          float a = alph[i][h];
          acc[h][0] = fmaf(a, f0, acc[h][0]);
          acc[h][1] = fmaf(a, f1, acc[h][1]);
          acc[h][2] = fmaf(a, f2, acc[h][2]);
          acc[h][3] = fmaf(a, f3, acc[h][3]);
        }
      }
    }
    __syncthreads();
  }
  if (t < 192) {
#pragma unroll
    for (int h = 0; h < 8; ++h) {
      uint2 o;
      o.x = pk2(acc[h][0], acc[h][1]);
      o.y = pk2(acc[h][2], acc[h][3]);
      *(uint2*)(y + ((size_t)n * 8 + h) * kH + c0) = o;
    }
  }
}

// ---------------- workspace init ----------------
__global__ void init_kernel(uint4* __restrict__ xb4, int* __restrict__ deg,
                            int* __restrict__ winner) {
  int i = blockIdx.x * 256 + threadIdx.x;
  if (i < kNN * kH * 2 / 16) xb4[i] = (uint4){0u, 0u, 0u, 0u};
  if (i < kNN) deg[i] = 0;
  if (i < kNB) winner[i] = -1;
}

// ---------------- degree count + winner (merged) ----------------
__global__ void deg_winner_kernel(const int* __restrict__ ei, int* __restrict__ deg,
                                  const int* __restrict__ business_idx,
                                  int* __restrict__ winner) {
  int e = blockIdx.x * 256 + threadIdx.x;
  if (e < kET) {
    int dst = (e < kE) ? ei[kE + e] : (e - kE);
    atomicAdd(&deg[dst], 1);
  }
  if (e < kB) atomicMax(&winner[business_idx[e] - kNU], e);
}

__global__ __launch_bounds__(1024) void scan_kernel(const int* __restrict__ deg,
                                                    int* __restrict__ rowptr,
                                                    int* __restrict__ cursor) {
  __shared__ int sums[1024];
  int t = threadIdx.x;
  int v0 = deg[t * 3], v1 = deg[t * 3 + 1], v2 = deg[t * 3 + 2];
  int s = v0 + v1 + v2;
  sums[t] = s;
  __syncthreads();
  for (int o = 1; o < 1024; o <<= 1) {
    int xv = (t >= o) ? sums[t - o] : 0;
    __syncthreads();
    sums[t] += xv;
    __syncthreads();
  }
  int excl = sums[t] - s;
  rowptr[t * 3] = excl;          cursor[t * 3] = excl;
  rowptr[t * 3 + 1] = excl + v0; cursor[t * 3 + 1] = excl + v0;
  rowptr[t * 3 + 2] = excl + v0 + v1; cursor[t * 3 + 2] = excl + v0 + v1;
  if (t == 1023) rowptr[kNN] = excl + s;
}

__global__ void fill_kernel(const int* __restrict__ ei, int* __restrict__ cursor,
                            int* __restrict__ cols) {
  int e = blockIdx.x * 256 + threadIdx.x;
  if (e >= kET) return;
  int src, dst;
  if (e < kE) { src = ei[e]; dst = ei[kE + e]; } else { src = dst = e - kE; }
  int pos = atomicAdd(&cursor[dst], 1);
  cols[pos] = src;
}

// ---------------- node feature build ----------------
__global__ void build_x_kernel(const int* __restrict__ user_idx,
                               const float* __restrict__ user_table,
                               const int* __restrict__ winner,
                               const float* __restrict__ text_emb,
                               const float* __restrict__ img_emb,
                               const float* __restrict__ biz_feats,
                               const float* __restrict__ W_bf,
                               const float* __restrict__ b_bf,
                               const float* __restrict__ biz_table,
                               __hip_bfloat16* __restrict__ xb) {
  int b = blockIdx.x;
  if (b < kNU) {
    int node = user_idx[b];
    for (int c = threadIdx.x; c < kH; c += blockDim.x)
      xb[(size_t)node * kH + c] = __float2bfloat16(user_table[(size_t)node * kH + c]);
  } else {
    int m = b - kNU;
    int w = winner[m];
    if (w < 0) return;
    int node = kNU + m;
    float f0 = biz_feats[w * 3], f1 = biz_feats[w * 3 + 1], f2 = biz_feats[w * 3 + 2];
    for (int c = threadIdx.x; c < kH; c += blockDim.x) {
      float meta = f0 * W_bf[c] + f1 * W_bf[kH + c] + f2 * W_bf[2 * kH + c] + b_bf[c];
      float v = (text_emb[(size_t)w * kH + c] + img_emb[(size_t)w * kH + c] + meta +
                 biz_table[(size_t)m * kH + c]) * 0.25f;
      xb[(size_t)node * kH + c] = __float2bfloat16(v);
    }
  }
}

// ---------------- GAT layer-2 segment softmax + aggregation (wave per node) ----------
__global__ __launch_bounds__(256) void gat_agg_kernel(
    const int* __restrict__ rowptr, const int* __restrict__ cols,
    const float* __restrict__ s_src, const float* __restrict__ s_dst,
    const __hip_bfloat16* __restrict__ h, const float* __restrict__ bias,
    float* __restrict__ out_f, int total) {
  const int pair = blockIdx.x * 4 + (threadIdx.x >> 6);
  if (pair >= total) return;
  const int lane = threadIdx.x & 63;
  const int n = pair;
  const int beg = rowptr[n], end = rowptr[n + 1];
  const float sdv = s_dst[pair];

  float m = -3.402823466e38f;
  for (int i = beg + lane; i < end; i += 64) {
    float e = s_src[cols[i]] + sdv;
    e = (e > 0.f) ? e : 0.2f * e;
    m = fmaxf(m, e);
  }
#pragma unroll
  for (int o = 32; o; o >>= 1) m = fmaxf(m, __shfl_xor(m, o));

  float dsum = 0.f;
  for (int i = beg + lane; i < end; i += 64) {
    float e = s_src[cols[i]] + sdv;
    e = (e > 0.f) ? e : 0.2f * e;
    dsum += expf(e - m);
  }
#pragma unroll
  for (int o = 32; o; o >>= 1) dsum += __shfl_xor(dsum, o);
  const float rdsum = 1.f / (dsum + 1e-16f);

  float a[12];
#pragma unroll
  for (int q = 0; q < 12; ++q) a[q] = 0.f;
  const size_t hoff = (size_t)lane * 4;
  for (int i = beg; i < end; ++i) {
    int src = cols[i];
    float e = s_src[src] + sdv;
    e = (e > 0.f) ? e : 0.2f * e;
    float wgt = expf(e - m) * rdsum;
    const __hip_bfloat16* hp = h + (size_t)src * kH + hoff;
#pragma unroll
    for (int j = 0; j < 3; ++j) {
      uint2 v = *(const uint2*)(hp + j * 256);
      a[j * 4 + 0] = fmaf(wgt, blo(v.x), a[j * 4 + 0]);
      a[j * 4 + 1] = fmaf(wgt, bhi(v.x), a[j * 4 + 1]);
      a[j * 4 + 2] = fmaf(wgt, blo(v.y), a[j * 4 + 2]);
      a[j * 4 + 3] = fmaf(wgt, bhi(v.y), a[j * 4 + 3]);
    }
  }
  const size_t ob = (size_t)n * kH + hoff;
#pragma unroll
  for (int j = 0; j < 3; ++j) {
#pragma unroll
    for (int q = 0; q < 4; ++q)
      out_f[ob + j * 256 + q] = a[j * 4 + q] + bias[hoff + j * 256 + q];
  }
}

// ---------------- MLP head ----------------
__global__ void cat_kernel(const float* __restrict__ xf, const float* __restrict__ text_emb,
                           const float* __restrict__ img_emb, const int* __restrict__ user_idx,
                           const int* __restrict__ business_idx, __hip_bfloat16* __restrict__ cat) {
  int b = blockIdx.x;
  int u = user_idx[b], z = business_idx[b];
  __hip_bfloat16* crow = cat + (size_t)b * 4 * kH;
  for (int c = threadIdx.x; c < kH; c += blockDim.x) {
    crow[c] = __float2bfloat16(xf[(size_t)u * kH + c]);
    crow[kH + c] = __float2bfloat16(xf[(size_t)z * kH + c]);
    crow[2 * kH + c] = __float2bfloat16(text_emb[(size_t)b * kH + c]);
    crow[3 * kH + c] = __float2bfloat16(img_emb[(size_t)b * kH + c]);
  }
}

__global__ __launch_bounds__(256) void final_kernel(const float* __restrict__ m2,
                                                    const float* __restrict__ Wf3,
                                                    const float* __restrict__ bf3,
                                                    float* __restrict__ out) {
  int b = (blockIdx.x * 256 + threadIdx.x) >> 6;
  int lane = threadIdx.x & 63;
  if (b >= kB) return;
  float s = 0.f;
  for (int c = lane; c < kH; c += 64) s = fmaf(m2[(size_t)b * kH + c], Wf3[c], s);
#pragma unroll
  for (int o = 32; o; o >>= 1) s += __shfl_down(s, o);
  if (lane == 0) out[b] = s + bf3[0];
}

}  // namespace

extern "C" void kernel_launch(void* const* d_in, const int* in_sizes, int n_in,
                              void* d_out, int out_size, void* d_ws, size_t ws_size,
                              hipStream_t stream) {
  const float* text_cls = (const float*)d_in[0];
  const float* img_cls = (const float*)d_in[1];
  const float* biz_feats = (const float*)d_in[2];
  const float* W_text = (const float*)d_in[3];
  const float* b_text = (const float*)d_in[4];
  const float* W_img = (const float*)d_in[5];
  const float* b_img = (const float*)d_in[6];
  const float* W_bf = (const float*)d_in[7];
  const float* b_bf = (const float*)d_in[8];
  const float* user_table = (const float*)d_in[9];
  const float* biz_table = (const float*)d_in[10];
  const float* W1 = (const float*)d_in[11];
  const float* att_src1 = (const float*)d_in[12];
  const float* att_dst1 = (const float*)d_in[13];
  const float* b1 = (const float*)d_in[14];
  const float* W2 = (const float*)d_in[15];
  const float* att_src2 = (const float*)d_in[16];
  const float* att_dst2 = (const float*)d_in[17];
  const float* b2 = (const float*)d_in[18];
  const float* Wf1 = (const float*)d_in[19];
  const float* bf1 = (const float*)d_in[20];
  const float* Wf2 = (const float*)d_in[21];
  const float* bf2 = (const float*)d_in[22];
  const float* Wf3 = (const float*)d_in[23];
  const float* bf3 = (const float*)d_in[24];
  const int* user_idx = (const int*)d_in[25];
  const int* business_idx = (const int*)d_in[26];
  const int* edge_index = (const int*)d_in[27];
  float* out = (float*)d_out;
  (void)in_sizes; (void)n_in; (void)out_size; (void)ws_size;

  char* base = (char*)d_ws;
  size_t off = 0;
  auto alloc = [&](size_t bytes) -> void* {
    void* p = base + off;
    off = (off + bytes + 255) & ~(size_t)255;
    return p;
  };
  __hip_bfloat16* xb = (__hip_bfloat16*)alloc((size_t)kNN * kH * 2);
  __hip_bfloat16* text_bf = (__hip_bfloat16*)alloc((size_t)kB * kH * 2);
  __hip_bfloat16* imgm_bf = (__hip_bfloat16*)alloc((size_t)kB * kH * 2);
  float* text_emb = (float*)alloc((size_t)kB * kH * 4);
  float* img_emb = (float*)alloc((size_t)kB * kH * 4);
  __hip_bfloat16* Wtt = (__hip_bfloat16*)alloc((size_t)kH * kH * 2);
  __hip_bfloat16* Wit = (__hip_bfloat16*)alloc((size_t)kH * kH * 2);
  __hip_bfloat16* W1t = (__hip_bfloat16*)alloc((size_t)kHeads * kH * kH * 2);
  __hip_bfloat16* W2t = (__hip_bfloat16*)alloc((size_t)kH * kHeads * kH * 2);
  __hip_bfloat16* Wf1t = (__hip_bfloat16*)alloc((size_t)2 * kH * 4 * kH * 2);
  __hip_bfloat16* Wf2t = (__hip_bfloat16*)alloc((size_t)kH * 2 * kH * 2);
  float* wa = (float*)alloc((size_t)2 * kHeads * kH * 4);
  __hip_bfloat16* y = (__hip_bfloat16*)alloc((size_t)kNN * kHeads * kH * 2);
  __hip_bfloat16* x2 = (__hip_bfloat16*)alloc((size_t)kNN * kHeads * kH * 2);
  __hip_bfloat16* h2 = (__hip_bfloat16*)alloc((size_t)kNN * kH * 2);
  float* xf = (float*)alloc((size_t)kNN * kH * 4);
  float* s1s = (float*)alloc((size_t)kNN * kHeads * 4);
  float* s1d = (float*)alloc((size_t)kNN * kHeads * 4);
  float* s2s = (float*)alloc((size_t)kNN * 4);
  float* s2d = (float*)alloc((size_t)kNN * 4);
  __hip_bfloat16* catb = (__hip_bfloat16*)alloc((size_t)kB * 4 * kH * 2);
  __hip_bfloat16* m1 = (__hip_bfloat16*)alloc((size_t)kB * 2 * kH * 2);
  float* m2 = (float*)alloc((size_t)kB * kH * 4);
  int* deg = (int*)alloc((size_t)kNN * 4);
  int* rowptr = (int*)alloc((size_t)(kNN + 1) * 4);
  int* cursor = (int*)alloc((size_t)kNN * 4);
  int* cols = (int*)alloc((size_t)kET * 4);
  int* winner = (int*)alloc((size_t)kNB * 4);

  // split-K partials aliased over y (dead after gemm_head): exact fit for S=4
  float* part = (float*)y;

  // init: zero xb, deg; winner = -1
  init_kernel<<<(kNN * kH * 2 / 16 + 255) / 256, 256, 0, stream>>>((uint4*)xb, deg, winner);

  // batched weight transposes + input prep in one launch
  TJobs tj;
  tj.in[0] = W_text; tj.out[0] = Wtt;  tj.K[0] = kH;          tj.N[0] = kH;
  tj.in[1] = W_img;  tj.out[1] = Wit;  tj.K[1] = kH;          tj.N[1] = kH;
  tj.in[2] = W1;     tj.out[2] = W1t;  tj.K[2] = kH;          tj.N[2] = kHeads * kH;
  tj.in[3] = W2;     tj.out[3] = W2t;  tj.K[3] = kHeads * kH; tj.N[3] = kH;
  tj.in[4] = Wf1;    tj.out[4] = Wf1t; tj.K[4] = 4 * kH;      tj.N[4] = 2 * kH;
  tj.in[5] = Wf2;    tj.out[5] = Wf2t; tj.K[5] = 2 * kH;      tj.N[5] = kH;
  tj.start[0] = 0;
  for (int q = 0; q < 6; ++q)
    tj.start[q + 1] = tj.start[q] + (tj.K[q] / 32) * (tj.N[q] / 32);
  const int prep_blocks = (kB * kH + 255) / 256;
  transp_prep_kernel<<<tj.start[6] + prep_blocks, 256, 0, stream>>>(tj, text_cls, img_cls,
                                                                    text_bf, imgm_bf);

  // projected attention vectors for layer 1
  wa1_kernel<<<(kHeads * kH) / 4, 256, 0, stream>>>(W1, att_src1, att_dst1, wa);

  // encoders, batched in z (64x128 tile, 192 blocks/z)
  mfma_gemm_dual<64, 128, 2, 4><<<dim3(kH / 128, kB / 64, 2), 256, 0, stream>>>(
      text_bf, Wtt, b_text, text_emb, imgm_bf, Wit, b_img, img_emb, kH, kH);

  // CSR degree + winner
  deg_winner_kernel<<<(kET + 255) / 256, 256, 0, stream>>>(edge_index, deg, business_idx, winner);
  scan_kernel<<<1, 1024, 0, stream>>>(deg, rowptr, cursor);
  fill_kernel<<<(kET + 255) / 256, 256, 0, stream>>>(edge_index, cursor, cols);

  // node features
  build_x_kernel<<<kNN, 256, 0, stream>>>(user_idx, user_table, winner, text_emb, img_emb,
                                          biz_feats, W_bf, b_bf, biz_table, xb);

  // GAT layer 1, x-space: scores from x -> alpha -> 768-dim aggregate -> per-head GEMM
  s1_kernel<<<kNN, 256, 0, stream>>>(xb, wa, s1s, s1d);
  agg1x_kernel<<<kNN, 256, 0, stream>>>(rowptr, cols, s1s, s1d, xb, y);
  gemm_head<128, 128, 4, 4><<<dim3(kH / 128, kNN / 128, kHeads), 256, 0, stream>>>(
      y, W1t, b1, x2);

  // GAT layer 2 (1 head): split-K, then fused reduce+scores2, then aggregate
  mfma_gemm_splitk<64, 128, 2, 4><<<dim3(kH / 128, kNN / 64, kSplitK), 256, 0, stream>>>(
      x2, W2t, part, kNN, kH, kHeads * kH, kHeads * kH / kSplitK);
  reduce_scores2_kernel<<<kNN, 192, 0, stream>>>(part, att_src2, att_dst2, h2, s2s, s2d);
  gat_agg_kernel<<<kNN / 4, 256, 0, stream>>>(rowptr, cols, s2s, s2d, h2, b2, xf, kNN);

  // MLP head
  cat_kernel<<<kB, 256, 0, stream>>>(xf, text_emb, img_emb, user_idx, business_idx, catb);
  mfma_gemm<64, 128, 2, 4, __hip_bfloat16, true><<<dim3(2 * kH / 128, kB / 64), 256, 0, stream>>>(
      catb, Wf1t, bf1, m1, 2 * kH, 4 * kH, 1);
  mfma_gemm<64, 64, 2, 2, float, true><<<dim3(kH / 64, kB / 64), 256, 0, stream>>>(
      m1, Wf2t, bf2, m2, kH, 2 * kH, 1);
  final_kernel<<<(kB * 64 + 255) / 256, 256, 0, stream>>>(m2, Wf3, bf3, out);
}

// Round 8
// 270.674 us; speedup vs baseline: 1.3518x; 1.1292x over previous
//
#include <hip/hip_runtime.h>
#include <hip/hip_bf16.h>

namespace {

constexpr int kB = 1024;      // batch
constexpr int kNU = 1024;     // num users
constexpr int kNB = 2048;     // num businesses
constexpr int kNN = 3072;     // total nodes
constexpr int kE = 16384;     // raw edges
constexpr int kET = kE + kNN; // edges + self loops = 19456
constexpr int kH = 768;
constexpr int kHeads = 8;
constexpr int kSplitK = 4;    // GAT2 split-K factor

typedef __attribute__((ext_vector_type(8))) short bf16x8_t;
typedef __attribute__((ext_vector_type(4))) float f32x4_t;

__device__ __forceinline__ float tof(float x) { return x; }
__device__ __forceinline__ float tof(__hip_bfloat16 x) { return __bfloat162float(x); }
__device__ __forceinline__ void stor(float* p, float v) { *p = v; }
__device__ __forceinline__ void stor(__hip_bfloat16* p, float v) { *p = __float2bfloat16(v); }

__device__ __forceinline__ float blo(unsigned u) {
  union { unsigned u; float f; } c; c.u = u << 16; return c.f;
}
__device__ __forceinline__ float bhi(unsigned u) {
  union { unsigned u; float f; } c; c.u = u & 0xffff0000u; return c.f;
}

__device__ __forceinline__ unsigned pk2(float a, float b) {
  union { __hip_bfloat16 h[2]; unsigned u; } c;
  c.h[0] = __float2bfloat16(a); c.h[1] = __float2bfloat16(b);
  return c.u;
}

__device__ __forceinline__ void gload_lds16(const void* g, void* l) {
  __builtin_amdgcn_global_load_lds(
      (const __attribute__((address_space(1))) void*)g,
      (__attribute__((address_space(3))) void*)l, 16, 0, 0);
}

// ---------------- 2-phase MFMA GEMM (proven engine) with lda/ldc ----------------
template <int BM, int BN, int FM, int FN, typename TC>
__device__ __forceinline__ void gemm_body(
    const __hip_bfloat16* __restrict__ A, const __hip_bfloat16* __restrict__ Bt,
    const float* __restrict__ bias, TC* __restrict__ C,
    int K, int lda, int ldc, int act, int bx, int by) {
  __shared__ __align__(16) __hip_bfloat16 As[2][BM][32];
  __shared__ __align__(16) __hip_bfloat16 Bs[2][BN][32];
  const int t = threadIdx.x;
  const int w = t >> 6, lane = t & 63;
  const int wm = w >> 1, wn = w & 1;
  const int bm = by * BM, bn = bx * BN;
  const int lr = lane & 15, lg = lane >> 4;

  f32x4_t acc[FM][FN];
#pragma unroll
  for (int m = 0; m < FM; ++m)
#pragma unroll
    for (int n = 0; n < FN; ++n) acc[m][n] = (f32x4_t){0.f, 0.f, 0.f, 0.f};

  auto stage = [&](int buf, int kt) {
    const int k0 = kt << 5;
#pragma unroll
    for (int i = 0; i < BM / 64; ++i) {
      int L = i * 256 + t;
      gload_lds16(A + (size_t)(bm + (L >> 2)) * lda + k0 + (L & 3) * 8,
                  (char*)(&As[buf][0][0]) + ((size_t)(i * 256 + w * 64)) * 16);
    }
#pragma unroll
    for (int i = 0; i < BN / 64; ++i) {
      int L = i * 256 + t;
      gload_lds16(Bt + (size_t)(bn + (L >> 2)) * K + k0 + (L & 3) * 8,
                  (char*)(&Bs[buf][0][0]) + ((size_t)(i * 256 + w * 64)) * 16);
    }
  };

  const int NT = K >> 5;
  stage(0, 0);
  __syncthreads();
  for (int kt = 0; kt < NT; ++kt) {
    const int cur = kt & 1;
    if (kt + 1 < NT) stage(cur ^ 1, kt + 1);
    bf16x8_t af[FM], bv[FN];
#pragma unroll
    for (int m = 0; m < FM; ++m)
      af[m] = *(const bf16x8_t*)&As[cur][wm * FM * 16 + m * 16 + lr][lg * 8];
#pragma unroll
    for (int n = 0; n < FN; ++n)
      bv[n] = *(const bf16x8_t*)&Bs[cur][wn * FN * 16 + n * 16 + lr][lg * 8];
#pragma unroll
    for (int m = 0; m < FM; ++m)
#pragma unroll
      for (int n = 0; n < FN; ++n)
        acc[m][n] = __builtin_amdgcn_mfma_f32_16x16x32_bf16(af[m], bv[n], acc[m][n], 0, 0, 0);
    __syncthreads();
  }

#pragma unroll
  for (int m = 0; m < FM; ++m) {
    const int row0 = bm + wm * FM * 16 + m * 16 + lg * 4;
#pragma unroll
    for (int n = 0; n < FN; ++n) {
      const int cn = bn + wn * FN * 16 + n * 16 + lr;
      const float bvv = bias ? bias[cn] : 0.f;
#pragma unroll
      for (int r = 0; r < 4; ++r) {
        float v = acc[m][n][r] + bvv;
        if (act) v = fmaxf(v, 0.f);
        stor(&C[(size_t)(row0 + r) * ldc + cn], v);
      }
    }
  }
}

__device__ __forceinline__ void swz_xy(bool mfast, int& bx, int& by) {
  const int nwg = gridDim.x * gridDim.y;
  const int orig = blockIdx.y * gridDim.x + blockIdx.x;
  const int swz = (orig & 7) * (nwg >> 3) + (orig >> 3);
  if (mfast) { by = swz % gridDim.y; bx = swz / gridDim.y; }
  else       { bx = swz % gridDim.x; by = swz / gridDim.x; }
}

template <int BM, int BN, int FM, int FN, typename TC, bool MFAST>
__global__ __launch_bounds__(256) void mfma_gemm(
    const __hip_bfloat16* __restrict__ A, const __hip_bfloat16* __restrict__ Bt,
    const float* __restrict__ bias, TC* __restrict__ C,
    int N, int K, int act) {
  int bx, by;
  swz_xy(MFAST, bx, by);
  gemm_body<BM, BN, FM, FN, TC>(A, Bt, bias, C, K, K, N, act, bx, by);
}

template <int BM, int BN, int FM, int FN>
__global__ __launch_bounds__(256) void mfma_gemm_dual(
    const __hip_bfloat16* __restrict__ A0, const __hip_bfloat16* __restrict__ Bt0,
    const float* __restrict__ bias0, float* __restrict__ C0,
    const __hip_bfloat16* __restrict__ A1, const __hip_bfloat16* __restrict__ Bt1,
    const float* __restrict__ bias1, float* __restrict__ C1,
    int N, int K) {
  int bx, by;
  swz_xy(true, bx, by);
  const __hip_bfloat16* A = blockIdx.z ? A1 : A0;
  const __hip_bfloat16* Bt = blockIdx.z ? Bt1 : Bt0;
  const float* bias = blockIdx.z ? bias1 : bias0;
  float* C = blockIdx.z ? C1 : C0;
  gemm_body<BM, BN, FM, FN, float>(A, Bt, bias, C, K, K, N, 0, bx, by);
}

// per-head projection, HEAD->XCD PINNED: blockIdx.x = head = dispatch%8 = XCD.
// Each XCD streams one head's A slice once; its 1.2MB B slice stays L2-resident.
template <int BM, int BN, int FM, int FN>
__global__ __launch_bounds__(256) void gemm_head(
    const __hip_bfloat16* __restrict__ y, const __hip_bfloat16* __restrict__ W1t,
    const float* __restrict__ b1, __hip_bfloat16* __restrict__ x2) {
  const int hd = blockIdx.x;            // 0..7
  const int tile = blockIdx.y;          // 0..143
  const int bx = tile % (kH / BN);      // bx fastest: consecutive tiles share A panel
  const int by = tile / (kH / BN);
  gemm_body<BM, BN, FM, FN, __hip_bfloat16>(
      y + (size_t)hd * kH, W1t + (size_t)hd * kH * kH, b1 + hd * kH,
      x2 + (size_t)hd * kH, kH, kHeads * kH, kHeads * kH, 1, bx, by);
}

// split-K variant: f32 partials
template <int BM, int BN, int FM, int FN>
__global__ __launch_bounds__(256) void mfma_gemm_splitk(
    const __hip_bfloat16* __restrict__ A, const __hip_bfloat16* __restrict__ Bt,
    float* __restrict__ Cpart, int M, int N, int K, int KC) {
  __shared__ __align__(16) __hip_bfloat16 As[2][BM][32];
  __shared__ __align__(16) __hip_bfloat16 Bs[2][BN][32];
  int bx, by;
  swz_xy(false, bx, by);
  const int t = threadIdx.x;
  const int w = t >> 6, lane = t & 63;
  const int wm = w >> 1, wn = w & 1;
  const int bm = by * BM, bn = bx * BN;
  const int kbeg = blockIdx.z * KC;
  const int lr = lane & 15, lg = lane >> 4;

  f32x4_t acc[FM][FN];
#pragma unroll
  for (int m = 0; m < FM; ++m)
#pragma unroll
    for (int n = 0; n < FN; ++n) acc[m][n] = (f32x4_t){0.f, 0.f, 0.f, 0.f};

  auto stage = [&](int buf, int kt) {
    const int k0 = kbeg + (kt << 5);
#pragma unroll
    for (int i = 0; i < BM / 64; ++i) {
      int L = i * 256 + t;
      gload_lds16(A + (size_t)(bm + (L >> 2)) * K + k0 + (L & 3) * 8,
                  (char*)(&As[buf][0][0]) + ((size_t)(i * 256 + w * 64)) * 16);
    }
#pragma unroll
    for (int i = 0; i < BN / 64; ++i) {
      int L = i * 256 + t;
      gload_lds16(Bt + (size_t)(bn + (L >> 2)) * K + k0 + (L & 3) * 8,
                  (char*)(&Bs[buf][0][0]) + ((size_t)(i * 256 + w * 64)) * 16);
    }
  };

  const int NT = KC >> 5;
  stage(0, 0);
  __syncthreads();
  for (int kt = 0; kt < NT; ++kt) {
    const int cur = kt & 1;
    if (kt + 1 < NT) stage(cur ^ 1, kt + 1);
    bf16x8_t af[FM], bv[FN];
#pragma unroll
    for (int m = 0; m < FM; ++m)
      af[m] = *(const bf16x8_t*)&As[cur][wm * FM * 16 + m * 16 + lr][lg * 8];
#pragma unroll
    for (int n = 0; n < FN; ++n)
      bv[n] = *(const bf16x8_t*)&Bs[cur][wn * FN * 16 + n * 16 + lr][lg * 8];
#pragma unroll
    for (int m = 0; m < FM; ++m)
#pragma unroll
      for (int n = 0; n < FN; ++n)
        acc[m][n] = __builtin_amdgcn_mfma_f32_16x16x32_bf16(af[m], bv[n], acc[m][n], 0, 0, 0);
    __syncthreads();
  }

  float* Cp = Cpart + (size_t)blockIdx.z * M * N;
#pragma unroll
  for (int m = 0; m < FM; ++m) {
    const int row0 = bm + wm * FM * 16 + m * 16 + lg * 4;
#pragma unroll
    for (int n = 0; n < FN; ++n) {
      const int cn = bn + wn * FN * 16 + n * 16 + lr;
#pragma unroll
      for (int r = 0; r < 4; ++r) Cp[(size_t)(row0 + r) * N + cn] = acc[m][n][r];
    }
  }
}

// ---------------- fused split-K reduce + scores2 (one block per row) ----------------
__global__ __launch_bounds__(192) void reduce_scores2_kernel(
    const float* __restrict__ part, const float* __restrict__ att_src,
    const float* __restrict__ att_dst, __hip_bfloat16* __restrict__ h2,
    float* __restrict__ s_src, float* __restrict__ s_dst) {
  __shared__ float redS[3], redD[3];
  const int row = blockIdx.x;
  const int t = threadIdx.x;
  const int c = t * 4;
  const float* p = part + (size_t)row * kH + c;
  float4 s = *(const float4*)p;
#pragma unroll
  for (int z = 1; z < kSplitK; ++z) {
    float4 qv = *(const float4*)(p + (size_t)z * kNN * kH);
    s.x += qv.x; s.y += qv.y; s.z += qv.z; s.w += qv.w;
  }
  __hip_bfloat16 b0 = __float2bfloat16(s.x), b1 = __float2bfloat16(s.y);
  __hip_bfloat16 b2 = __float2bfloat16(s.z), b3 = __float2bfloat16(s.w);
  __hip_bfloat16* o = h2 + (size_t)row * kH + c;
  o[0] = b0; o[1] = b1; o[2] = b2; o[3] = b3;
  float f0 = tof(b0), f1 = tof(b1), f2 = tof(b2), f3 = tof(b3);
  float ss = f0 * att_src[c] + f1 * att_src[c + 1] + f2 * att_src[c + 2] + f3 * att_src[c + 3];
  float sd = f0 * att_dst[c] + f1 * att_dst[c + 1] + f2 * att_dst[c + 2] + f3 * att_dst[c + 3];
#pragma unroll
  for (int off = 32; off; off >>= 1) { ss += __shfl_down(ss, off); sd += __shfl_down(sd, off); }
  if ((t & 63) == 0) { redS[t >> 6] = ss; redD[t >> 6] = sd; }
  __syncthreads();
  if (t == 0) {
    s_src[row] = redS[0] + redS[1] + redS[2];
    s_dst[row] = redD[0] + redD[1] + redD[2];
  }
}

// ---------------- split-K reduce + bias + relu -> bf16 (for Wf1) ----------------
__global__ void reduce_relu_kernel(const float* __restrict__ part,
                                   const float* __restrict__ bias,
                                   __hip_bfloat16* __restrict__ outb, int MN4, int N) {
  int i = blockIdx.x * 256 + threadIdx.x;
  if (i >= MN4) return;
  float4 s = ((const float4*)part)[i];
  float4 p = ((const float4*)part)[(size_t)MN4 + i];
  int c = (i * 4) % N;
  float v0 = fmaxf(s.x + p.x + bias[c], 0.f);
  float v1 = fmaxf(s.y + p.y + bias[c + 1], 0.f);
  float v2 = fmaxf(s.z + p.z + bias[c + 2], 0.f);
  float v3 = fmaxf(s.w + p.w + bias[c + 3], 0.f);
  uint2 o;
  o.x = pk2(v0, v1); o.y = pk2(v2, v3);
  *(uint2*)(outb + (size_t)i * 4) = o;
}

// ---------------- split-K reduce + bias + relu + dot(Wf3) -> out (fused final) ------
__global__ __launch_bounds__(192) void reduce_final_kernel(
    const float* __restrict__ part, const float* __restrict__ bias,
    const float* __restrict__ Wf3, const float* __restrict__ bf3,
    float* __restrict__ out) {
  __shared__ float red[3];
  const int row = blockIdx.x;
  const int t = threadIdx.x;
  const int c = t * 4;
  const float* p0 = part + (size_t)row * kH + c;
  const float* p1 = p0 + (size_t)kB * kH;
  float4 a = *(const float4*)p0;
  float4 b = *(const float4*)p1;
  float v0 = fmaxf(a.x + b.x + bias[c], 0.f);
  float v1 = fmaxf(a.y + b.y + bias[c + 1], 0.f);
  float v2 = fmaxf(a.z + b.z + bias[c + 2], 0.f);
  float v3 = fmaxf(a.w + b.w + bias[c + 3], 0.f);
  float s = v0 * Wf3[c] + v1 * Wf3[c + 1] + v2 * Wf3[c + 2] + v3 * Wf3[c + 3];
#pragma unroll
  for (int off = 32; off; off >>= 1) s += __shfl_down(s, off);
  if ((t & 63) == 0) red[t >> 6] = s;
  __syncthreads();
  if (t == 0) out[row] = red[0] + red[1] + red[2] + bf3[0];
}

// ---------------- mega-kernel: weight transposes + input prep + wa1 ----------------
struct TJobs {
  const float* in[6];
  __hip_bfloat16* out[6];
  int K[6];
  int N[6];
  int start[7];
};

__global__ __launch_bounds__(256) void transp_prep_kernel(
    TJobs j, const float* __restrict__ text_cls, const float* __restrict__ img_cls,
    __hip_bfloat16* __restrict__ text_bf, __hip_bfloat16* __restrict__ imgm_bf,
    int prep_blocks, const float* __restrict__ W1, const float* __restrict__ a_src,
    const float* __restrict__ a_dst, float* __restrict__ wa) {
  __shared__ float tl[32][33];
  const int bid = blockIdx.x;
  const int t = threadIdx.x;
  if (bid >= j.start[6] + prep_blocks) {
    // wa1 region: gw over kHeads*kH, 4 waves/block
    int gw = ((bid - j.start[6] - prep_blocks) * 256 + t) >> 6;
    int lane = t & 63;
    if (gw >= kHeads * kH) return;
    int i = gw >> 3, hd = gw & 7;
    const float* wrow = W1 + (size_t)i * (kHeads * kH) + hd * kH;
    const float* as = a_src + (size_t)hd * kH;
    const float* ad = a_dst + (size_t)hd * kH;
    float ss = 0.f, sd = 0.f;
    for (int c = lane; c < kH; c += 64) {
      float wv = wrow[c];
      ss = fmaf(wv, as[c], ss);
      sd = fmaf(wv, ad[c], sd);
    }
#pragma unroll
    for (int o = 32; o; o >>= 1) { ss += __shfl_down(ss, o); sd += __shfl_down(sd, o); }
    if (lane == 0) {
      wa[hd * kH + i] = ss;
      wa[kHeads * kH + hd * kH + i] = sd;
    }
    return;
  }
  if (bid >= j.start[6]) {
    int idx = (bid - j.start[6]) * 256 + t;
    if (idx < kB * kH) {
      text_bf[idx] = __float2bfloat16(text_cls[idx]);
      int b = idx / kH, c = idx - b * kH;
      const float* p = img_cls + (size_t)b * 3 * kH + c;
      imgm_bf[idx] = __float2bfloat16((p[0] + p[kH] + p[2 * kH]) * (1.f / 3.f));
    }
    return;
  }
  int idx = 0;
#pragma unroll
  for (int q = 1; q < 6; ++q)
    if (bid >= j.start[q]) idx = q;
  const int tile = bid - j.start[idx];
  const int N = j.N[idx], K = j.K[idx];
  const int tilesN = N >> 5;
  const int n0 = (tile % tilesN) << 5, k0 = (tile / tilesN) << 5;
  const float* in = j.in[idx];
  __hip_bfloat16* out = j.out[idx];
  const int r = t >> 3, c = (t & 7) * 4;
#pragma unroll
  for (int i = 0; i < 4; ++i) tl[r][c + i] = in[(size_t)(k0 + r) * N + n0 + c + i];
  __syncthreads();
  __hip_bfloat16* op = out + (size_t)(n0 + r) * K + k0 + c;
#pragma unroll
  for (int i = 0; i < 4; ++i) op[i] = __float2bfloat16(tl[c + i][r]);
}

// ---------------- s1: layer-1 scores from x (768-dim) ----------------
__global__ __launch_bounds__(256) void s1_kernel(const __hip_bfloat16* __restrict__ xb,
                                                 const float* __restrict__ wa,
                                                 float* __restrict__ s1s,
                                                 float* __restrict__ s1d) {
  __shared__ unsigned xrow[kH / 2];
  const int n = blockIdx.x;
  const int t = threadIdx.x;
  const unsigned* xp = (const unsigned*)(xb + (size_t)n * kH);
  if (t < 128) { xrow[t] = xp[t]; xrow[t + 128] = xp[t + 128]; xrow[t + 256] = xp[t + 256]; }
  __syncthreads();
  const int w = t >> 6, lane = t & 63;
  const float* ws0 = wa + (size_t)w * kH;
  const float* wd0 = wa + (size_t)(kHeads + w) * kH;
  const float* ws1 = wa + (size_t)(w + 4) * kH;
  const float* wd1 = wa + (size_t)(kHeads + w + 4) * kH;
  float s0 = 0.f, d0 = 0.f, s1 = 0.f, d1 = 0.f;
  for (int u = lane; u < kH / 2; u += 64) {
    unsigned v = xrow[u];
    float f0 = blo(v), f1 = bhi(v);
    int c = u * 2;
    s0 = fmaf(f0, ws0[c], fmaf(f1, ws0[c + 1], s0));
    d0 = fmaf(f0, wd0[c], fmaf(f1, wd0[c + 1], d0));
    s1 = fmaf(f0, ws1[c], fmaf(f1, ws1[c + 1], s1));
    d1 = fmaf(f0, wd1[c], fmaf(f1, wd1[c + 1], d1));
  }
#pragma unroll
  for (int o = 32; o; o >>= 1) {
    s0 += __shfl_down(s0, o); d0 += __shfl_down(d0, o);
    s1 += __shfl_down(s1, o); d1 += __shfl_down(d1, o);
  }
  if (lane == 0) {
    s1s[n * 8 + w] = s0;     s1d[n * 8 + w] = d0;
    s1s[n * 8 + w + 4] = s1; s1d[n * 8 + w + 4] = d1;
  }
}

// ---------------- layer-1 aggregation in x-space ----------------
__global__ __launch_bounds__(256) void agg1x_kernel(
    const int* __restrict__ rowptr, const int* __restrict__ cols,
    const float* __restrict__ s1s, const float* __restrict__ s1d,
    const __hip_bfloat16* __restrict__ xb, __hip_bfloat16* __restrict__ y) {
  __shared__ float mh[8], rdh[8], sdl[8];
  __shared__ float alph[128][9];
  const int n = blockIdx.x;
  const int t = threadIdx.x, w = t >> 6, lane = t & 63;
  const int beg = rowptr[n], end = rowptr[n + 1];
  if (t < 8) sdl[t] = s1d[n * 8 + t];
  __syncthreads();
#pragma unroll
  for (int p = 0; p < 2; ++p) {
    const int h = w + p * 4;
    const float sd = sdl[h];
    float m = -3.402823466e38f;
    for (int i = beg + lane; i < end; i += 64) {
      float e = s1s[(size_t)cols[i] * 8 + h] + sd;
      e = (e > 0.f) ? e : 0.2f * e;
      m = fmaxf(m, e);
    }
#pragma unroll
    for (int o = 32; o; o >>= 1) m = fmaxf(m, __shfl_xor(m, o));
    float ds = 0.f;
    for (int i = beg + lane; i < end; i += 64) {
      float e = s1s[(size_t)cols[i] * 8 + h] + sd;
      e = (e > 0.f) ? e : 0.2f * e;
      ds += expf(e - m);
    }
#pragma unroll
    for (int o = 32; o; o >>= 1) ds += __shfl_xor(ds, o);
    if (lane == 0) { mh[h] = m; rdh[h] = 1.f / (ds + 1e-16f); }
  }
  __syncthreads();

  float acc[8][4];
#pragma unroll
  for (int h = 0; h < 8; ++h)
#pragma unroll
    for (int q = 0; q < 4; ++q) acc[h][q] = 0.f;
  const int c0 = t * 4;

  for (int chunk = beg; chunk < end; chunk += 128) {
    const int cnt = min(128, end - chunk);
#pragma unroll
    for (int p = 0; p < 2; ++p) {
      const int h = w + p * 4;
      const float sd = sdl[h], m = mh[h], rd = rdh[h];
      for (int i = lane; i < cnt; i += 64) {
        float e = s1s[(size_t)cols[chunk + i] * 8 + h] + sd;
        e = (e > 0.f) ? e : 0.2f * e;
        alph[i][h] = expf(e - m) * rd;
      }
    }
    __syncthreads();
    if (t < 192) {
      for (int i = 0; i < cnt; ++i) {
        int src = cols[chunk + i];
        uint2 v = *(const uint2*)(xb + (size_t)src * kH + c0);
        float f0 = blo(v.x), f1 = bhi(v.x), f2 = blo(v.y), f3 = bhi(v.y);
#pragma unroll
        for (int h = 0; h < 8; ++h) {
          float a = alph[i][h];
          acc[h][0] = fmaf(a, f0, acc[h][0]);
          acc[h][1] = fmaf(a, f1, acc[h][1]);
          acc[h][2] = fmaf(a, f2, acc[h][2]);
          acc[h][3] = fmaf(a, f3, acc[h][3]);
        }
      }
    }
    __syncthreads();
  }
  if (t < 192) {
#pragma unroll
    for (int h = 0; h < 8; ++h) {
      uint2 o;
      o.x = pk2(acc[h][0], acc[h][1]);
      o.y = pk2(acc[h][2], acc[h][3]);
      *(uint2*)(y + ((size_t)n * 8 + h) * kH + c0) = o;
    }
  }
}

// ---------------- workspace init ----------------
__global__ void init_kernel(uint4* __restrict__ xb4, int* __restrict__ deg,
                            int* __restrict__ winner) {
  int i = blockIdx.x * 256 + threadIdx.x;
  if (i < kNN * kH * 2 / 16) xb4[i] = (uint4){0u, 0u, 0u, 0u};
  if (i < kNN) deg[i] = 0;
  if (i < kNB) winner[i] = -1;
}

// ---------------- degree count + winner (merged) ----------------
__global__ void deg_winner_kernel(const int* __restrict__ ei, int* __restrict__ deg,
                                  const int* __restrict__ business_idx,
                                  int* __restrict__ winner) {
  int e = blockIdx.x * 256 + threadIdx.x;
  if (e < kET) {
    int dst = (e < kE) ? ei[kE + e] : (e - kE);
    atomicAdd(&deg[dst], 1);
  }
  if (e < kB) atomicMax(&winner[business_idx[e] - kNU], e);
}

__global__ __launch_bounds__(1024) void scan_kernel(const int* __restrict__ deg,
                                                    int* __restrict__ rowptr,
                                                    int* __restrict__ cursor) {
  __shared__ int sums[1024];
  int t = threadIdx.x;
  int v0 = deg[t * 3], v1 = deg[t * 3 + 1], v2 = deg[t * 3 + 2];
  int s = v0 + v1 + v2;
  sums[t] = s;
  __syncthreads();
  for (int o = 1; o < 1024; o <<= 1) {
    int xv = (t >= o) ? sums[t - o] : 0;
    __syncthreads();
    sums[t] += xv;
    __syncthreads();
  }
  int excl = sums[t] - s;
  rowptr[t * 3] = excl;          cursor[t * 3] = excl;
  rowptr[t * 3 + 1] = excl + v0; cursor[t * 3 + 1] = excl + v0;
  rowptr[t * 3 + 2] = excl + v0 + v1; cursor[t * 3 + 2] = excl + v0 + v1;
  if (t == 1023) rowptr[kNN] = excl + s;
}

__global__ void fill_kernel(const int* __restrict__ ei, int* __restrict__ cursor,
                            int* __restrict__ cols) {
  int e = blockIdx.x * 256 + threadIdx.x;
  if (e >= kET) return;
  int src, dst;
  if (e < kE) { src = ei[e]; dst = ei[kE + e]; } else { src = dst = e - kE; }
  int pos = atomicAdd(&cursor[dst], 1);
  cols[pos] = src;
}

// ---------------- node feature build ----------------
__global__ void build_x_kernel(const int* __restrict__ user_idx,
                               const float* __restrict__ user_table,
                               const int* __restrict__ winner,
                               const float* __restrict__ text_emb,
                               const float* __restrict__ img_emb,
                               const float* __restrict__ biz_feats,
                               const float* __restrict__ W_bf,
                               const float* __restrict__ b_bf,
                               const float* __restrict__ biz_table,
                               __hip_bfloat16* __restrict__ xb) {
  int b = blockIdx.x;
  if (b < kNU) {
    int node = user_idx[b];
    for (int c = threadIdx.x; c < kH; c += blockDim.x)
      xb[(size_t)node * kH + c] = __float2bfloat16(user_table[(size_t)node * kH + c]);
  } else {
    int m = b - kNU;
    int w = winner[m];
    if (w < 0) return;
    int node = kNU + m;
    float f0 = biz_feats[w * 3], f1 = biz_feats[w * 3 + 1], f2 = biz_feats[w * 3 + 2];
    for (int c = threadIdx.x; c < kH; c += blockDim.x) {
      float meta = f0 * W_bf[c] + f1 * W_bf[kH + c] + f2 * W_bf[2 * kH + c] + b_bf[c];
      float v = (text_emb[(size_t)w * kH + c] + img_emb[(size_t)w * kH + c] + meta +
                 biz_table[(size_t)m * kH + c]) * 0.25f;
      xb[(size_t)node * kH + c] = __float2bfloat16(v);
    }
  }
}

// ---------------- GAT layer-2 segment softmax + aggregation (wave per node) ----------
__global__ __launch_bounds__(256) void gat_agg_kernel(
    const int* __restrict__ rowptr, const int* __restrict__ cols,
    const float* __restrict__ s_src, const float* __restrict__ s_dst,
    const __hip_bfloat16* __restrict__ h, const float* __restrict__ bias,
    float* __restrict__ out_f, int total) {
  const int pair = blockIdx.x * 4 + (threadIdx.x >> 6);
  if (pair >= total) return;
  const int lane = threadIdx.x & 63;
  const int n = pair;
  const int beg = rowptr[n], end = rowptr[n + 1];
  const float sdv = s_dst[pair];

  float m = -3.402823466e38f;
  for (int i = beg + lane; i < end; i += 64) {
    float e = s_src[cols[i]] + sdv;
    e = (e > 0.f) ? e : 0.2f * e;
    m = fmaxf(m, e);
  }
#pragma unroll
  for (int o = 32; o; o >>= 1) m = fmaxf(m, __shfl_xor(m, o));

  float dsum = 0.f;
  for (int i = beg + lane; i < end; i += 64) {
    float e = s_src[cols[i]] + sdv;
    e = (e > 0.f) ? e : 0.2f * e;
    dsum += expf(e - m);
  }
#pragma unroll
  for (int o = 32; o; o >>= 1) dsum += __shfl_xor(dsum, o);
  const float rdsum = 1.f / (dsum + 1e-16f);

  float a[12];
#pragma unroll
  for (int q = 0; q < 12; ++q) a[q] = 0.f;
  const size_t hoff = (size_t)lane * 4;
  for (int i = beg; i < end; ++i) {
    int src = cols[i];
    float e = s_src[src] + sdv;
    e = (e > 0.f) ? e : 0.2f * e;
    float wgt = expf(e - m) * rdsum;
    const __hip_bfloat16* hp = h + (size_t)src * kH + hoff;
#pragma unroll
    for (int j = 0; j < 3; ++j) {
      uint2 v = *(const uint2*)(hp + j * 256);
      a[j * 4 + 0] = fmaf(wgt, blo(v.x), a[j * 4 + 0]);
      a[j * 4 + 1] = fmaf(wgt, bhi(v.x), a[j * 4 + 1]);
      a[j * 4 + 2] = fmaf(wgt, blo(v.y), a[j * 4 + 2]);
      a[j * 4 + 3] = fmaf(wgt, bhi(v.y), a[j * 4 + 3]);
    }
  }
  const size_t ob = (size_t)n * kH + hoff;
#pragma unroll
  for (int j = 0; j < 3; ++j) {
#pragma unroll
    for (int q = 0; q < 4; ++q)
      out_f[ob + j * 256 + q] = a[j * 4 + q] + bias[hoff + j * 256 + q];
  }
}

// ---------------- MLP head ----------------
__global__ void cat_kernel(const float* __restrict__ xf, const float* __restrict__ text_emb,
                           const float* __restrict__ img_emb, const int* __restrict__ user_idx,
                           const int* __restrict__ business_idx, __hip_bfloat16* __restrict__ cat) {
  int b = blockIdx.x;
  int u = user_idx[b], z = business_idx[b];
  __hip_bfloat16* crow = cat + (size_t)b * 4 * kH;
  for (int c = threadIdx.x; c < kH; c += blockDim.x) {
    crow[c] = __float2bfloat16(xf[(size_t)u * kH + c]);
    crow[kH + c] = __float2bfloat16(xf[(size_t)z * kH + c]);
    crow[2 * kH + c] = __float2bfloat16(text_emb[(size_t)b * kH + c]);
    crow[3 * kH + c] = __float2bfloat16(img_emb[(size_t)b * kH + c]);
  }
}

}  // namespace

extern "C" void kernel_launch(void* const* d_in, const int* in_sizes, int n_in,
                              void* d_out, int out_size, void* d_ws, size_t ws_size,
                              hipStream_t stream) {
  const float* text_cls = (const float*)d_in[0];
  const float* img_cls = (const float*)d_in[1];
  const float* biz_feats = (const float*)d_in[2];
  const float* W_text = (const float*)d_in[3];
  const float* b_text = (const float*)d_in[4];
  const float* W_img = (const float*)d_in[5];
  const float* b_img = (const float*)d_in[6];
  const float* W_bf = (const float*)d_in[7];
  const float* b_bf = (const float*)d_in[8];
  const float* user_table = (const float*)d_in[9];
  const float* biz_table = (const float*)d_in[10];
  const float* W1 = (const float*)d_in[11];
  const float* att_src1 = (const float*)d_in[12];
  const float* att_dst1 = (const float*)d_in[13];
  const float* b1 = (const float*)d_in[14];
  const float* W2 = (const float*)d_in[15];
  const float* att_src2 = (const float*)d_in[16];
  const float* att_dst2 = (const float*)d_in[17];
  const float* b2 = (const float*)d_in[18];
  const float* Wf1 = (const float*)d_in[19];
  const float* bf1 = (const float*)d_in[20];
  const float* Wf2 = (const float*)d_in[21];
  const float* bf2 = (const float*)d_in[22];
  const float* Wf3 = (const float*)d_in[23];
  const float* bf3 = (const float*)d_in[24];
  const int* user_idx = (const int*)d_in[25];
  const int* business_idx = (const int*)d_in[26];
  const int* edge_index = (const int*)d_in[27];
  float* out = (float*)d_out;
  (void)in_sizes; (void)n_in; (void)out_size; (void)ws_size;

  char* base = (char*)d_ws;
  size_t off = 0;
  auto alloc = [&](size_t bytes) -> void* {
    void* p = base + off;
    off = (off + bytes + 255) & ~(size_t)255;
    return p;
  };
  __hip_bfloat16* xb = (__hip_bfloat16*)alloc((size_t)kNN * kH * 2);
  __hip_bfloat16* text_bf = (__hip_bfloat16*)alloc((size_t)kB * kH * 2);
  __hip_bfloat16* imgm_bf = (__hip_bfloat16*)alloc((size_t)kB * kH * 2);
  float* text_emb = (float*)alloc((size_t)kB * kH * 4);
  float* img_emb = (float*)alloc((size_t)kB * kH * 4);
  __hip_bfloat16* Wtt = (__hip_bfloat16*)alloc((size_t)kH * kH * 2);
  __hip_bfloat16* Wit = (__hip_bfloat16*)alloc((size_t)kH * kH * 2);
  __hip_bfloat16* W1t = (__hip_bfloat16*)alloc((size_t)kHeads * kH * kH * 2);
  __hip_bfloat16* W2t = (__hip_bfloat16*)alloc((size_t)kH * kHeads * kH * 2);
  __hip_bfloat16* Wf1t = (__hip_bfloat16*)alloc((size_t)2 * kH * 4 * kH * 2);
  __hip_bfloat16* Wf2t = (__hip_bfloat16*)alloc((size_t)kH * 2 * kH * 2);
  float* wa = (float*)alloc((size_t)2 * kHeads * kH * 4);
  __hip_bfloat16* y = (__hip_bfloat16*)alloc((size_t)kNN * kHeads * kH * 2);
  __hip_bfloat16* x2 = (__hip_bfloat16*)alloc((size_t)kNN * kHeads * kH * 2);
  __hip_bfloat16* h2 = (__hip_bfloat16*)alloc((size_t)kNN * kH * 2);
  float* xf = (float*)alloc((size_t)kNN * kH * 4);
  float* s1s = (float*)alloc((size_t)kNN * kHeads * 4);
  float* s1d = (float*)alloc((size_t)kNN * kHeads * 4);
  float* s2s = (float*)alloc((size_t)kNN * 4);
  float* s2d = (float*)alloc((size_t)kNN * 4);
  __hip_bfloat16* catb = (__hip_bfloat16*)alloc((size_t)kB * 4 * kH * 2);
  __hip_bfloat16* m1 = (__hip_bfloat16*)alloc((size_t)kB * 2 * kH * 2);
  float* m2 = (float*)alloc((size_t)kB * kH * 4);
  int* deg = (int*)alloc((size_t)kNN * 4);
  int* rowptr = (int*)alloc((size_t)(kNN + 1) * 4);
  int* cursor = (int*)alloc((size_t)kNN * 4);
  int* cols = (int*)alloc((size_t)kET * 4);
  int* winner = (int*)alloc((size_t)kNB * 4);
  (void)m2;

  // partials buffer aliased over y: GAT2 S=4 (37.75MB) fits exactly; Wf1 S=2
  // (12.6MB) and Wf2 S=2 (6.3MB) reuse it after it goes dead.
  float* part = (float*)y;

  init_kernel<<<(kNN * kH * 2 / 16 + 255) / 256, 256, 0, stream>>>((uint4*)xb, deg, winner);

  // mega-kernel: weight transposes + input prep + wa1
  TJobs tj;
  tj.in[0] = W_text; tj.out[0] = Wtt;  tj.K[0] = kH;          tj.N[0] = kH;
  tj.in[1] = W_img;  tj.out[1] = Wit;  tj.K[1] = kH;          tj.N[1] = kH;
  tj.in[2] = W1;     tj.out[2] = W1t;  tj.K[2] = kH;          tj.N[2] = kHeads * kH;
  tj.in[3] = W2;     tj.out[3] = W2t;  tj.K[3] = kHeads * kH; tj.N[3] = kH;
  tj.in[4] = Wf1;    tj.out[4] = Wf1t; tj.K[4] = 4 * kH;      tj.N[4] = 2 * kH;
  tj.in[5] = Wf2;    tj.out[5] = Wf2t; tj.K[5] = 2 * kH;      tj.N[5] = kH;
  tj.start[0] = 0;
  for (int q = 0; q < 6; ++q)
    tj.start[q + 1] = tj.start[q] + (tj.K[q] / 32) * (tj.N[q] / 32);
  const int prep_blocks = (kB * kH + 255) / 256;
  const int wa_blocks = (kHeads * kH) / 4;
  transp_prep_kernel<<<tj.start[6] + prep_blocks + wa_blocks, 256, 0, stream>>>(
      tj, text_cls, img_cls, text_bf, imgm_bf, prep_blocks, W1, att_src1, att_dst1, wa);

  // encoders, batched in z
  mfma_gemm_dual<64, 128, 2, 4><<<dim3(kH / 128, kB / 64, 2), 256, 0, stream>>>(
      text_bf, Wtt, b_text, text_emb, imgm_bf, Wit, b_img, img_emb, kH, kH);

  // CSR degree + winner
  deg_winner_kernel<<<(kET + 255) / 256, 256, 0, stream>>>(edge_index, deg, business_idx, winner);
  scan_kernel<<<1, 1024, 0, stream>>>(deg, rowptr, cursor);
  fill_kernel<<<(kET + 255) / 256, 256, 0, stream>>>(edge_index, cursor, cols);

  // node features
  build_x_kernel<<<kNN, 256, 0, stream>>>(user_idx, user_table, winner, text_emb, img_emb,
                                          biz_feats, W_bf, b_bf, biz_table, xb);

  // GAT layer 1, x-space: scores -> alpha-aggregate (768-dim) -> head-pinned GEMM
  s1_kernel<<<kNN, 256, 0, stream>>>(xb, wa, s1s, s1d);
  agg1x_kernel<<<kNN, 256, 0, stream>>>(rowptr, cols, s1s, s1d, xb, y);
  gemm_head<128, 128, 4, 4><<<dim3(kHeads, (kNN / 128) * (kH / 128)), 256, 0, stream>>>(
      y, W1t, b1, x2);

  // GAT layer 2 (1 head): split-K, fused reduce+scores2, aggregate
  mfma_gemm_splitk<64, 128, 2, 4><<<dim3(kH / 128, kNN / 64, kSplitK), 256, 0, stream>>>(
      x2, W2t, part, kNN, kH, kHeads * kH, kHeads * kH / kSplitK);
  reduce_scores2_kernel<<<kNN, 192, 0, stream>>>(part, att_src2, att_dst2, h2, s2s, s2d);
  gat_agg_kernel<<<kNN / 4, 256, 0, stream>>>(rowptr, cols, s2s, s2d, h2, b2, xf, kNN);

  // MLP head: cat -> Wf1 (split-K S=2) -> Wf2 (split-K S=2) -> fused final
  cat_kernel<<<kB, 256, 0, stream>>>(xf, text_emb, img_emb, user_idx, business_idx, catb);
  mfma_gemm_splitk<64, 128, 2, 4><<<dim3(2 * kH / 128, kB / 64, 2), 256, 0, stream>>>(
      catb, Wf1t, part, kB, 2 * kH, 4 * kH, 2 * kH);
  reduce_relu_kernel<<<(kB * 2 * kH / 4 + 255) / 256, 256, 0, stream>>>(
      part, bf1, m1, kB * 2 * kH / 4, 2 * kH);
  mfma_gemm_splitk<64, 128, 2, 4><<<dim3(kH / 128, kB / 64, 2), 256, 0, stream>>>(
      m1, Wf2t, part, kB, kH, 2 * kH, kH);
  reduce_final_kernel<<<kB, 192, 0, stream>>>(part, bf2, Wf3, bf3, out);
}

// Round 9
// 263.579 us; speedup vs baseline: 1.3881x; 1.0269x over previous
//
#include <hip/hip_runtime.h>
#include <hip/hip_bf16.h>

namespace {

constexpr int kB = 1024;      // batch
constexpr int kNU = 1024;     // num users
constexpr int kNB = 2048;     // num businesses
constexpr int kNN = 3072;     // total nodes
constexpr int kE = 16384;     // raw edges
constexpr int kET = kE + kNN; // edges + self loops = 19456
constexpr int kH = 768;
constexpr int kHeads = 8;
constexpr int kS2 = 8;        // GAT2 split-K factor (XCD-pinned K-chunks)

typedef __attribute__((ext_vector_type(8))) short bf16x8_t;
typedef __attribute__((ext_vector_type(4))) float f32x4_t;

__device__ __forceinline__ float tof(float x) { return x; }
__device__ __forceinline__ float tof(__hip_bfloat16 x) { return __bfloat162float(x); }
__device__ __forceinline__ void stor(float* p, float v) { *p = v; }
__device__ __forceinline__ void stor(__hip_bfloat16* p, float v) { *p = __float2bfloat16(v); }

__device__ __forceinline__ float blo(unsigned u) {
  union { unsigned u; float f; } c; c.u = u << 16; return c.f;
}
__device__ __forceinline__ float bhi(unsigned u) {
  union { unsigned u; float f; } c; c.u = u & 0xffff0000u; return c.f;
}

__device__ __forceinline__ unsigned pk2(float a, float b) {
  union { __hip_bfloat16 h[2]; unsigned u; } c;
  c.h[0] = __float2bfloat16(a); c.h[1] = __float2bfloat16(b);
  return c.u;
}

__device__ __forceinline__ void gload_lds16(const void* g, void* l) {
  __builtin_amdgcn_global_load_lds(
      (const __attribute__((address_space(1))) void*)g,
      (__attribute__((address_space(3))) void*)l, 16, 0, 0);
}

// ---------------- 2-phase MFMA GEMM (proven engine) with lda/ldc ----------------
template <int BM, int BN, int FM, int FN, typename TC>
__device__ __forceinline__ void gemm_body(
    const __hip_bfloat16* __restrict__ A, const __hip_bfloat16* __restrict__ Bt,
    const float* __restrict__ bias, TC* __restrict__ C,
    int K, int lda, int ldc, int act, int bx, int by) {
  __shared__ __align__(16) __hip_bfloat16 As[2][BM][32];
  __shared__ __align__(16) __hip_bfloat16 Bs[2][BN][32];
  const int t = threadIdx.x;
  const int w = t >> 6, lane = t & 63;
  const int wm = w >> 1, wn = w & 1;
  const int bm = by * BM, bn = bx * BN;
  const int lr = lane & 15, lg = lane >> 4;

  f32x4_t acc[FM][FN];
#pragma unroll
  for (int m = 0; m < FM; ++m)
#pragma unroll
    for (int n = 0; n < FN; ++n) acc[m][n] = (f32x4_t){0.f, 0.f, 0.f, 0.f};

  auto stage = [&](int buf, int kt) {
    const int k0 = kt << 5;
#pragma unroll
    for (int i = 0; i < BM / 64; ++i) {
      int L = i * 256 + t;
      gload_lds16(A + (size_t)(bm + (L >> 2)) * lda + k0 + (L & 3) * 8,
                  (char*)(&As[buf][0][0]) + ((size_t)(i * 256 + w * 64)) * 16);
    }
#pragma unroll
    for (int i = 0; i < BN / 64; ++i) {
      int L = i * 256 + t;
      gload_lds16(Bt + (size_t)(bn + (L >> 2)) * K + k0 + (L & 3) * 8,
                  (char*)(&Bs[buf][0][0]) + ((size_t)(i * 256 + w * 64)) * 16);
    }
  };

  const int NT = K >> 5;
  stage(0, 0);
  __syncthreads();
  for (int kt = 0; kt < NT; ++kt) {
    const int cur = kt & 1;
    if (kt + 1 < NT) stage(cur ^ 1, kt + 1);
    bf16x8_t af[FM], bv[FN];
#pragma unroll
    for (int m = 0; m < FM; ++m)
      af[m] = *(const bf16x8_t*)&As[cur][wm * FM * 16 + m * 16 + lr][lg * 8];
#pragma unroll
    for (int n = 0; n < FN; ++n)
      bv[n] = *(const bf16x8_t*)&Bs[cur][wn * FN * 16 + n * 16 + lr][lg * 8];
#pragma unroll
    for (int m = 0; m < FM; ++m)
#pragma unroll
      for (int n = 0; n < FN; ++n)
        acc[m][n] = __builtin_amdgcn_mfma_f32_16x16x32_bf16(af[m], bv[n], acc[m][n], 0, 0, 0);
    __syncthreads();
  }

#pragma unroll
  for (int m = 0; m < FM; ++m) {
    const int row0 = bm + wm * FM * 16 + m * 16 + lg * 4;
#pragma unroll
    for (int n = 0; n < FN; ++n) {
      const int cn = bn + wn * FN * 16 + n * 16 + lr;
      const float bvv = bias ? bias[cn] : 0.f;
#pragma unroll
      for (int r = 0; r < 4; ++r) {
        float v = acc[m][n][r] + bvv;
        if (act) v = fmaxf(v, 0.f);
        stor(&C[(size_t)(row0 + r) * ldc + cn], v);
      }
    }
  }
}

__device__ __forceinline__ void swz_xy(bool mfast, int& bx, int& by) {
  const int nwg = gridDim.x * gridDim.y;
  const int orig = blockIdx.y * gridDim.x + blockIdx.x;
  const int swz = (orig & 7) * (nwg >> 3) + (orig >> 3);
  if (mfast) { by = swz % gridDim.y; bx = swz / gridDim.y; }
  else       { bx = swz % gridDim.x; by = swz / gridDim.x; }
}

template <int BM, int BN, int FM, int FN>
__global__ __launch_bounds__(256) void mfma_gemm_dual(
    const __hip_bfloat16* __restrict__ A0, const __hip_bfloat16* __restrict__ Bt0,
    const float* __restrict__ bias0, float* __restrict__ C0,
    const __hip_bfloat16* __restrict__ A1, const __hip_bfloat16* __restrict__ Bt1,
    const float* __restrict__ bias1, float* __restrict__ C1,
    int N, int K) {
  int bx, by;
  swz_xy(true, bx, by);
  const __hip_bfloat16* A = blockIdx.z ? A1 : A0;
  const __hip_bfloat16* Bt = blockIdx.z ? Bt1 : Bt0;
  const float* bias = blockIdx.z ? bias1 : bias0;
  float* C = blockIdx.z ? C1 : C0;
  gemm_body<BM, BN, FM, FN, float>(A, Bt, bias, C, K, K, N, 0, bx, by);
}

// per-head projection, HEAD->XCD PINNED: blockIdx.x = head = dispatch%8 = XCD.
template <int BM, int BN, int FM, int FN>
__global__ __launch_bounds__(256) void gemm_head(
    const __hip_bfloat16* __restrict__ y, const __hip_bfloat16* __restrict__ W1t,
    const float* __restrict__ b1, __hip_bfloat16* __restrict__ x2) {
  const int hd = blockIdx.x;            // 0..7
  const int tile = blockIdx.y;          // 0..143
  const int bx = tile % (kH / BN);      // bx fastest: consecutive tiles share A panel
  const int by = tile / (kH / BN);
  gemm_body<BM, BN, FM, FN, __hip_bfloat16>(
      y + (size_t)hd * kH, W1t + (size_t)hd * kH * kH, b1 + hd * kH,
      x2 + (size_t)hd * kH, kH, kHeads * kH, kHeads * kH, 1, bx, by);
}

// split-K, K-CHUNK->XCD PINNED: blockIdx.x = k-chunk = dispatch%8 = XCD.
// Each XCD's working set = A-chunk (M*KC*2B) + B-chunk (N*KC*2B) -> L2-resident.
template <int BM, int BN, int FM, int FN, int S>
__global__ __launch_bounds__(256) void mfma_gemm_kpin(
    const __hip_bfloat16* __restrict__ A, const __hip_bfloat16* __restrict__ Bt,
    float* __restrict__ Cpart, int M, int N, int K) {
  __shared__ __align__(16) __hip_bfloat16 As[2][BM][32];
  __shared__ __align__(16) __hip_bfloat16 Bs[2][BN][32];
  const int kc = blockIdx.x;            // 0..S-1
  const int tile = blockIdx.y;
  const int tilesN = N / BN;
  const int bx = tile % tilesN;         // bx fastest: share A panel, sweep B
  const int by = tile / tilesN;
  const int KC = K / S;
  const int kbeg = kc * KC;
  const int t = threadIdx.x;
  const int w = t >> 6, lane = t & 63;
  const int wm = w >> 1, wn = w & 1;
  const int bm = by * BM, bn = bx * BN;
  const int lr = lane & 15, lg = lane >> 4;

  f32x4_t acc[FM][FN];
#pragma unroll
  for (int m = 0; m < FM; ++m)
#pragma unroll
    for (int n = 0; n < FN; ++n) acc[m][n] = (f32x4_t){0.f, 0.f, 0.f, 0.f};

  auto stage = [&](int buf, int kt) {
    const int k0 = kbeg + (kt << 5);
#pragma unroll
    for (int i = 0; i < BM / 64; ++i) {
      int L = i * 256 + t;
      gload_lds16(A + (size_t)(bm + (L >> 2)) * K + k0 + (L & 3) * 8,
                  (char*)(&As[buf][0][0]) + ((size_t)(i * 256 + w * 64)) * 16);
    }
#pragma unroll
    for (int i = 0; i < BN / 64; ++i) {
      int L = i * 256 + t;
      gload_lds16(Bt + (size_t)(bn + (L >> 2)) * K + k0 + (L & 3) * 8,
                  (char*)(&Bs[buf][0][0]) + ((size_t)(i * 256 + w * 64)) * 16);
    }
  };

  const int NT = KC >> 5;
  stage(0, 0);
  __syncthreads();
  for (int kt = 0; kt < NT; ++kt) {
    const int cur = kt & 1;
    if (kt + 1 < NT) stage(cur ^ 1, kt + 1);
    bf16x8_t af[FM], bv[FN];
#pragma unroll
    for (int m = 0; m < FM; ++m)
      af[m] = *(const bf16x8_t*)&As[cur][wm * FM * 16 + m * 16 + lr][lg * 8];
#pragma unroll
    for (int n = 0; n < FN; ++n)
      bv[n] = *(const bf16x8_t*)&Bs[cur][wn * FN * 16 + n * 16 + lr][lg * 8];
#pragma unroll
    for (int m = 0; m < FM; ++m)
#pragma unroll
      for (int n = 0; n < FN; ++n)
        acc[m][n] = __builtin_amdgcn_mfma_f32_16x16x32_bf16(af[m], bv[n], acc[m][n], 0, 0, 0);
    __syncthreads();
  }

  float* Cp = Cpart + (size_t)kc * M * N;
#pragma unroll
  for (int m = 0; m < FM; ++m) {
    const int row0 = bm + wm * FM * 16 + m * 16 + lg * 4;
#pragma unroll
    for (int n = 0; n < FN; ++n) {
      const int cn = bn + wn * FN * 16 + n * 16 + lr;
#pragma unroll
      for (int r = 0; r < 4; ++r) Cp[(size_t)(row0 + r) * N + cn] = acc[m][n][r];
    }
  }
}

// generic split-K (swizzled) for the MLP GEMMs
template <int BM, int BN, int FM, int FN>
__global__ __launch_bounds__(256) void mfma_gemm_splitk(
    const __hip_bfloat16* __restrict__ A, const __hip_bfloat16* __restrict__ Bt,
    float* __restrict__ Cpart, int M, int N, int K, int KC) {
  __shared__ __align__(16) __hip_bfloat16 As[2][BM][32];
  __shared__ __align__(16) __hip_bfloat16 Bs[2][BN][32];
  int bx, by;
  swz_xy(false, bx, by);
  const int t = threadIdx.x;
  const int w = t >> 6, lane = t & 63;
  const int wm = w >> 1, wn = w & 1;
  const int bm = by * BM, bn = bx * BN;
  const int kbeg = blockIdx.z * KC;
  const int lr = lane & 15, lg = lane >> 4;

  f32x4_t acc[FM][FN];
#pragma unroll
  for (int m = 0; m < FM; ++m)
#pragma unroll
    for (int n = 0; n < FN; ++n) acc[m][n] = (f32x4_t){0.f, 0.f, 0.f, 0.f};

  auto stage = [&](int buf, int kt) {
    const int k0 = kbeg + (kt << 5);
#pragma unroll
    for (int i = 0; i < BM / 64; ++i) {
      int L = i * 256 + t;
      gload_lds16(A + (size_t)(bm + (L >> 2)) * K + k0 + (L & 3) * 8,
                  (char*)(&As[buf][0][0]) + ((size_t)(i * 256 + w * 64)) * 16);
    }
#pragma unroll
    for (int i = 0; i < BN / 64; ++i) {
      int L = i * 256 + t;
      gload_lds16(Bt + (size_t)(bn + (L >> 2)) * K + k0 + (L & 3) * 8,
                  (char*)(&Bs[buf][0][0]) + ((size_t)(i * 256 + w * 64)) * 16);
    }
  };

  const int NT = KC >> 5;
  stage(0, 0);
  __syncthreads();
  for (int kt = 0; kt < NT; ++kt) {
    const int cur = kt & 1;
    if (kt + 1 < NT) stage(cur ^ 1, kt + 1);
    bf16x8_t af[FM], bv[FN];
#pragma unroll
    for (int m = 0; m < FM; ++m)
      af[m] = *(const bf16x8_t*)&As[cur][wm * FM * 16 + m * 16 + lr][lg * 8];
#pragma unroll
    for (int n = 0; n < FN; ++n)
      bv[n] = *(const bf16x8_t*)&Bs[cur][wn * FN * 16 + n * 16 + lr][lg * 8];
#pragma unroll
    for (int m = 0; m < FM; ++m)
#pragma unroll
      for (int n = 0; n < FN; ++n)
        acc[m][n] = __builtin_amdgcn_mfma_f32_16x16x32_bf16(af[m], bv[n], acc[m][n], 0, 0, 0);
    __syncthreads();
  }

  float* Cp = Cpart + (size_t)blockIdx.z * M * N;
#pragma unroll
  for (int m = 0; m < FM; ++m) {
    const int row0 = bm + wm * FM * 16 + m * 16 + lg * 4;
#pragma unroll
    for (int n = 0; n < FN; ++n) {
      const int cn = bn + wn * FN * 16 + n * 16 + lr;
#pragma unroll
      for (int r = 0; r < 4; ++r) Cp[(size_t)(row0 + r) * N + cn] = acc[m][n][r];
    }
  }
}

// ---------------- fused split-K reduce (S=8) + scores2 (one block per row) ----------
__global__ __launch_bounds__(192) void reduce_scores2_kernel(
    const float* __restrict__ part, const float* __restrict__ att_src,
    const float* __restrict__ att_dst, __hip_bfloat16* __restrict__ h2,
    float* __restrict__ s_src, float* __restrict__ s_dst) {
  __shared__ float redS[3], redD[3];
  const int row = blockIdx.x;
  const int t = threadIdx.x;
  const int c = t * 4;
  const float* p = part + (size_t)row * kH + c;
  float4 s = *(const float4*)p;
#pragma unroll
  for (int z = 1; z < kS2; ++z) {
    float4 qv = *(const float4*)(p + (size_t)z * kNN * kH);
    s.x += qv.x; s.y += qv.y; s.z += qv.z; s.w += qv.w;
  }
  __hip_bfloat16 b0 = __float2bfloat16(s.x), b1 = __float2bfloat16(s.y);
  __hip_bfloat16 b2 = __float2bfloat16(s.z), b3 = __float2bfloat16(s.w);
  __hip_bfloat16* o = h2 + (size_t)row * kH + c;
  o[0] = b0; o[1] = b1; o[2] = b2; o[3] = b3;
  float f0 = tof(b0), f1 = tof(b1), f2 = tof(b2), f3 = tof(b3);
  float ss = f0 * att_src[c] + f1 * att_src[c + 1] + f2 * att_src[c + 2] + f3 * att_src[c + 3];
  float sd = f0 * att_dst[c] + f1 * att_dst[c + 1] + f2 * att_dst[c + 2] + f3 * att_dst[c + 3];
#pragma unroll
  for (int off = 32; off; off >>= 1) { ss += __shfl_down(ss, off); sd += __shfl_down(sd, off); }
  if ((t & 63) == 0) { redS[t >> 6] = ss; redD[t >> 6] = sd; }
  __syncthreads();
  if (t == 0) {
    s_src[row] = redS[0] + redS[1] + redS[2];
    s_dst[row] = redD[0] + redD[1] + redD[2];
  }
}

// ---------------- split-K reduce + bias + relu -> bf16 (for Wf1) ----------------
__global__ void reduce_relu_kernel(const float* __restrict__ part,
                                   const float* __restrict__ bias,
                                   __hip_bfloat16* __restrict__ outb, int MN4, int N) {
  int i = blockIdx.x * 256 + threadIdx.x;
  if (i >= MN4) return;
  float4 s = ((const float4*)part)[i];
  float4 p = ((const float4*)part)[(size_t)MN4 + i];
  int c = (i * 4) % N;
  float v0 = fmaxf(s.x + p.x + bias[c], 0.f);
  float v1 = fmaxf(s.y + p.y + bias[c + 1], 0.f);
  float v2 = fmaxf(s.z + p.z + bias[c + 2], 0.f);
  float v3 = fmaxf(s.w + p.w + bias[c + 3], 0.f);
  uint2 o;
  o.x = pk2(v0, v1); o.y = pk2(v2, v3);
  *(uint2*)(outb + (size_t)i * 4) = o;
}

// ---------------- split-K reduce + bias + relu + dot(Wf3) -> out ----------------
__global__ __launch_bounds__(192) void reduce_final_kernel(
    const float* __restrict__ part, const float* __restrict__ bias,
    const float* __restrict__ Wf3, const float* __restrict__ bf3,
    float* __restrict__ out) {
  __shared__ float red[3];
  const int row = blockIdx.x;
  const int t = threadIdx.x;
  const int c = t * 4;
  const float* p0 = part + (size_t)row * kH + c;
  const float* p1 = p0 + (size_t)kB * kH;
  float4 a = *(const float4*)p0;
  float4 b = *(const float4*)p1;
  float v0 = fmaxf(a.x + b.x + bias[c], 0.f);
  float v1 = fmaxf(a.y + b.y + bias[c + 1], 0.f);
  float v2 = fmaxf(a.z + b.z + bias[c + 2], 0.f);
  float v3 = fmaxf(a.w + b.w + bias[c + 3], 0.f);
  float s = v0 * Wf3[c] + v1 * Wf3[c + 1] + v2 * Wf3[c + 2] + v3 * Wf3[c + 3];
#pragma unroll
  for (int off = 32; off; off >>= 1) s += __shfl_down(s, off);
  if ((t & 63) == 0) red[t >> 6] = s;
  __syncthreads();
  if (t == 0) out[row] = red[0] + red[1] + red[2] + bf3[0];
}

// ---------------- mega-kernel: transposes + input prep + wa1 + init ----------------
struct TJobs {
  const float* in[6];
  __hip_bfloat16* out[6];
  int K[6];
  int N[6];
  int start[7];
};

__global__ __launch_bounds__(256) void transp_prep_kernel(
    TJobs j, const float* __restrict__ text_cls, const float* __restrict__ img_cls,
    __hip_bfloat16* __restrict__ text_bf, __hip_bfloat16* __restrict__ imgm_bf,
    int prep_blocks, const float* __restrict__ W1, const float* __restrict__ a_src,
    const float* __restrict__ a_dst, float* __restrict__ wa,
    int wa_blocks, uint4* __restrict__ xb4, int* __restrict__ deg,
    int* __restrict__ winner) {
  __shared__ float tl[32][33];
  const int bid = blockIdx.x;
  const int t = threadIdx.x;
  if (bid >= j.start[6] + prep_blocks + wa_blocks) {
    // init region: zero xb, deg; winner = -1
    int i = (bid - j.start[6] - prep_blocks - wa_blocks) * 256 + t;
    if (i < kNN * kH * 2 / 16) xb4[i] = (uint4){0u, 0u, 0u, 0u};
    if (i < kNN) deg[i] = 0;
    if (i < kNB) winner[i] = -1;
    return;
  }
  if (bid >= j.start[6] + prep_blocks) {
    // wa1 region
    int gw = ((bid - j.start[6] - prep_blocks) * 256 + t) >> 6;
    int lane = t & 63;
    if (gw >= kHeads * kH) return;
    int i = gw >> 3, hd = gw & 7;
    const float* wrow = W1 + (size_t)i * (kHeads * kH) + hd * kH;
    const float* as = a_src + (size_t)hd * kH;
    const float* ad = a_dst + (size_t)hd * kH;
    float ss = 0.f, sd = 0.f;
    for (int c = lane; c < kH; c += 64) {
      float wv = wrow[c];
      ss = fmaf(wv, as[c], ss);
      sd = fmaf(wv, ad[c], sd);
    }
#pragma unroll
    for (int o = 32; o; o >>= 1) { ss += __shfl_down(ss, o); sd += __shfl_down(sd, o); }
    if (lane == 0) {
      wa[hd * kH + i] = ss;
      wa[kHeads * kH + hd * kH + i] = sd;
    }
    return;
  }
  if (bid >= j.start[6]) {
    int idx = (bid - j.start[6]) * 256 + t;
    if (idx < kB * kH) {
      text_bf[idx] = __float2bfloat16(text_cls[idx]);
      int b = idx / kH, c = idx - b * kH;
      const float* p = img_cls + (size_t)b * 3 * kH + c;
      imgm_bf[idx] = __float2bfloat16((p[0] + p[kH] + p[2 * kH]) * (1.f / 3.f));
    }
    return;
  }
  int idx = 0;
#pragma unroll
  for (int q = 1; q < 6; ++q)
    if (bid >= j.start[q]) idx = q;
  const int tile = bid - j.start[idx];
  const int N = j.N[idx], K = j.K[idx];
  const int tilesN = N >> 5;
  const int n0 = (tile % tilesN) << 5, k0 = (tile / tilesN) << 5;
  const float* in = j.in[idx];
  __hip_bfloat16* out = j.out[idx];
  const int r = t >> 3, c = (t & 7) * 4;
#pragma unroll
  for (int i = 0; i < 4; ++i) tl[r][c + i] = in[(size_t)(k0 + r) * N + n0 + c + i];
  __syncthreads();
  __hip_bfloat16* op = out + (size_t)(n0 + r) * K + k0 + c;
#pragma unroll
  for (int i = 0; i < 4; ++i) op[i] = __float2bfloat16(tl[c + i][r]);
}

// ---------------- s1: layer-1 scores from x (768-dim) ----------------
__global__ __launch_bounds__(256) void s1_kernel(const __hip_bfloat16* __restrict__ xb,
                                                 const float* __restrict__ wa,
                                                 float* __restrict__ s1s,
                                                 float* __restrict__ s1d) {
  __shared__ unsigned xrow[kH / 2];
  const int n = blockIdx.x;
  const int t = threadIdx.x;
  const unsigned* xp = (const unsigned*)(xb + (size_t)n * kH);
  if (t < 128) { xrow[t] = xp[t]; xrow[t + 128] = xp[t + 128]; xrow[t + 256] = xp[t + 256]; }
  __syncthreads();
  const int w = t >> 6, lane = t & 63;
  const float* ws0 = wa + (size_t)w * kH;
  const float* wd0 = wa + (size_t)(kHeads + w) * kH;
  const float* ws1 = wa + (size_t)(w + 4) * kH;
  const float* wd1 = wa + (size_t)(kHeads + w + 4) * kH;
  float s0 = 0.f, d0 = 0.f, s1 = 0.f, d1 = 0.f;
  for (int u = lane; u < kH / 2; u += 64) {
    unsigned v = xrow[u];
    float f0 = blo(v), f1 = bhi(v);
    int c = u * 2;
    s0 = fmaf(f0, ws0[c], fmaf(f1, ws0[c + 1], s0));
    d0 = fmaf(f0, wd0[c], fmaf(f1, wd0[c + 1], d0));
    s1 = fmaf(f0, ws1[c], fmaf(f1, ws1[c + 1], s1));
    d1 = fmaf(f0, wd1[c], fmaf(f1, wd1[c + 1], d1));
  }
#pragma unroll
  for (int o = 32; o; o >>= 1) {
    s0 += __shfl_down(s0, o); d0 += __shfl_down(d0, o);
    s1 += __shfl_down(s1, o); d1 += __shfl_down(d1, o);
  }
  if (lane == 0) {
    s1s[n * 8 + w] = s0;     s1d[n * 8 + w] = d0;
    s1s[n * 8 + w + 4] = s1; s1d[n * 8 + w + 4] = d1;
  }
}

// ---------------- layer-1 aggregation in x-space ----------------
__global__ __launch_bounds__(256) void agg1x_kernel(
    const int* __restrict__ rowptr, const int* __restrict__ cols,
    const float* __restrict__ s1s, const float* __restrict__ s1d,
    const __hip_bfloat16* __restrict__ xb, __hip_bfloat16* __restrict__ y) {
  __shared__ float mh[8], rdh[8], sdl[8];
  __shared__ float alph[128][9];
  const int n = blockIdx.x;
  const int t = threadIdx.x, w = t >> 6, lane = t & 63;
  const int beg = rowptr[n], end = rowptr[n + 1];
  if (t < 8) sdl[t] = s1d[n * 8 + t];
  __syncthreads();
#pragma unroll
  for (int p = 0; p < 2; ++p) {
    const int h = w + p * 4;
    const float sd = sdl[h];
    float m = -3.402823466e38f;
    for (int i = beg + lane; i < end; i += 64) {
      float e = s1s[(size_t)cols[i] * 8 + h] + sd;
      e = (e > 0.f) ? e : 0.2f * e;
      m = fmaxf(m, e);
    }
#pragma unroll
    for (int o = 32; o; o >>= 1) m = fmaxf(m, __shfl_xor(m, o));
    float ds = 0.f;
    for (int i = beg + lane; i < end; i += 64) {
      float e = s1s[(size_t)cols[i] * 8 + h] + sd;
      e = (e > 0.f) ? e : 0.2f * e;
      ds += expf(e - m);
    }
#pragma unroll
    for (int o = 32; o; o >>= 1) ds += __shfl_xor(ds, o);
    if (lane == 0) { mh[h] = m; rdh[h] = 1.f / (ds + 1e-16f); }
  }
  __syncthreads();

  float acc[8][4];
#pragma unroll
  for (int h = 0; h < 8; ++h)
#pragma unroll
    for (int q = 0; q < 4; ++q) acc[h][q] = 0.f;
  const int c0 = t * 4;

  for (int chunk = beg; chunk < end; chunk += 128) {
    const int cnt = min(128, end - chunk);
#pragma unroll
    for (int p = 0; p < 2; ++p) {
      const int h = w + p * 4;
      const float sd = sdl[h], m = mh[h], rd = rdh[h];
      for (int i = lane; i < cnt; i += 64) {
        float e = s1s[(size_t)cols[chunk + i] * 8 + h] + sd;
        e = (e > 0.f) ? e : 0.2f * e;
        alph[i][h] = expf(e - m) * rd;
      }
    }
    __syncthreads();
    if (t < 192) {
      for (int i = 0; i < cnt; ++i) {
        int src = cols[chunk + i];
        uint2 v = *(const uint2*)(xb + (size_t)src * kH + c0);
        float f0 = blo(v.x), f1 = bhi(v.x), f2 = blo(v.y), f3 = bhi(v.y);
#pragma unroll
        for (int h = 0; h < 8; ++h) {
          float a = alph[i][h];
          acc[h][0] = fmaf(a, f0, acc[h][0]);
          acc[h][1] = fmaf(a, f1, acc[h][1]);
          acc[h][2] = fmaf(a, f2, acc[h][2]);
          acc[h][3] = fmaf(a, f3, acc[h][3]);
        }
      }
    }
    __syncthreads();
  }
  if (t < 192) {
#pragma unroll
    for (int h = 0; h < 8; ++h) {
      uint2 o;
      o.x = pk2(acc[h][0], acc[h][1]);
      o.y = pk2(acc[h][2], acc[h][3]);
      *(uint2*)(y + ((size_t)n * 8 + h) * kH + c0) = o;
    }
  }
}

// ---------------- degree count + winner (merged) ----------------
__global__ void deg_winner_kernel(const int* __restrict__ ei, int* __restrict__ deg,
                                  const int* __restrict__ business_idx,
                                  int* __restrict__ winner) {
  int e = blockIdx.x * 256 + threadIdx.x;
  if (e < kET) {
    int dst = (e < kE) ? ei[kE + e] : (e - kE);
    atomicAdd(&deg[dst], 1);
  }
  if (e < kB) atomicMax(&winner[business_idx[e] - kNU], e);
}

__global__ __launch_bounds__(1024) void scan_kernel(const int* __restrict__ deg,
                                                    int* __restrict__ rowptr,
                                                    int* __restrict__ cursor) {
  __shared__ int sums[1024];
  int t = threadIdx.x;
  int v0 = deg[t * 3], v1 = deg[t * 3 + 1], v2 = deg[t * 3 + 2];
  int s = v0 + v1 + v2;
  sums[t] = s;
  __syncthreads();
  for (int o = 1; o < 1024; o <<= 1) {
    int xv = (t >= o) ? sums[t - o] : 0;
    __syncthreads();
    sums[t] += xv;
    __syncthreads();
  }
  int excl = sums[t] - s;
  rowptr[t * 3] = excl;          cursor[t * 3] = excl;
  rowptr[t * 3 + 1] = excl + v0; cursor[t * 3 + 1] = excl + v0;
  rowptr[t * 3 + 2] = excl + v0 + v1; cursor[t * 3 + 2] = excl + v0 + v1;
  if (t == 1023) rowptr[kNN] = excl + s;
}

__global__ void fill_kernel(const int* __restrict__ ei, int* __restrict__ cursor,
                            int* __restrict__ cols) {
  int e = blockIdx.x * 256 + threadIdx.x;
  if (e >= kET) return;
  int src, dst;
  if (e < kE) { src = ei[e]; dst = ei[kE + e]; } else { src = dst = e - kE; }
  int pos = atomicAdd(&cursor[dst], 1);
  cols[pos] = src;
}

// ---------------- node feature build ----------------
__global__ void build_x_kernel(const int* __restrict__ user_idx,
                               const float* __restrict__ user_table,
                               const int* __restrict__ winner,
                               const float* __restrict__ text_emb,
                               const float* __restrict__ img_emb,
                               const float* __restrict__ biz_feats,
                               const float* __restrict__ W_bf,
                               const float* __restrict__ b_bf,
                               const float* __restrict__ biz_table,
                               __hip_bfloat16* __restrict__ xb) {
  int b = blockIdx.x;
  if (b < kNU) {
    int node = user_idx[b];
    for (int c = threadIdx.x; c < kH; c += blockDim.x)
      xb[(size_t)node * kH + c] = __float2bfloat16(user_table[(size_t)node * kH + c]);
  } else {
    int m = b - kNU;
    int w = winner[m];
    if (w < 0) return;
    int node = kNU + m;
    float f0 = biz_feats[w * 3], f1 = biz_feats[w * 3 + 1], f2 = biz_feats[w * 3 + 2];
    for (int c = threadIdx.x; c < kH; c += blockDim.x) {
      float meta = f0 * W_bf[c] + f1 * W_bf[kH + c] + f2 * W_bf[2 * kH + c] + b_bf[c];
      float v = (text_emb[(size_t)w * kH + c] + img_emb[(size_t)w * kH + c] + meta +
                 biz_table[(size_t)m * kH + c]) * 0.25f;
      xb[(size_t)node * kH + c] = __float2bfloat16(v);
    }
  }
}

// ---------------- GAT layer-2 segment softmax + aggregation (wave per node) ----------
__global__ __launch_bounds__(256) void gat_agg_kernel(
    const int* __restrict__ rowptr, const int* __restrict__ cols,
    const float* __restrict__ s_src, const float* __restrict__ s_dst,
    const __hip_bfloat16* __restrict__ h, const float* __restrict__ bias,
    float* __restrict__ out_f, int total) {
  const int pair = blockIdx.x * 4 + (threadIdx.x >> 6);
  if (pair >= total) return;
  const int lane = threadIdx.x & 63;
  const int n = pair;
  const int beg = rowptr[n], end = rowptr[n + 1];
  const float sdv = s_dst[pair];

  float m = -3.402823466e38f;
  for (int i = beg + lane; i < end; i += 64) {
    float e = s_src[cols[i]] + sdv;
    e = (e > 0.f) ? e : 0.2f * e;
    m = fmaxf(m, e);
  }
#pragma unroll
  for (int o = 32; o; o >>= 1) m = fmaxf(m, __shfl_xor(m, o));

  float dsum = 0.f;
  for (int i = beg + lane; i < end; i += 64) {
    float e = s_src[cols[i]] + sdv;
    e = (e > 0.f) ? e : 0.2f * e;
    dsum += expf(e - m);
  }
#pragma unroll
  for (int o = 32; o; o >>= 1) dsum += __shfl_xor(dsum, o);
  const float rdsum = 1.f / (dsum + 1e-16f);

  float a[12];
#pragma unroll
  for (int q = 0; q < 12; ++q) a[q] = 0.f;
  const size_t hoff = (size_t)lane * 4;
  for (int i = beg; i < end; ++i) {
    int src = cols[i];
    float e = s_src[src] + sdv;
    e = (e > 0.f) ? e : 0.2f * e;
    float wgt = expf(e - m) * rdsum;
    const __hip_bfloat16* hp = h + (size_t)src * kH + hoff;
#pragma unroll
    for (int j = 0; j < 3; ++j) {
      uint2 v = *(const uint2*)(hp + j * 256);
      a[j * 4 + 0] = fmaf(wgt, blo(v.x), a[j * 4 + 0]);
      a[j * 4 + 1] = fmaf(wgt, bhi(v.x), a[j * 4 + 1]);
      a[j * 4 + 2] = fmaf(wgt, blo(v.y), a[j * 4 + 2]);
      a[j * 4 + 3] = fmaf(wgt, bhi(v.y), a[j * 4 + 3]);
    }
  }
  const size_t ob = (size_t)n * kH + hoff;
#pragma unroll
  for (int j = 0; j < 3; ++j) {
#pragma unroll
    for (int q = 0; q < 4; ++q)
      out_f[ob + j * 256 + q] = a[j * 4 + q] + bias[hoff + j * 256 + q];
  }
}

// ---------------- MLP head ----------------
__global__ void cat_kernel(const float* __restrict__ xf, const float* __restrict__ text_emb,
                           const float* __restrict__ img_emb, const int* __restrict__ user_idx,
                           const int* __restrict__ business_idx, __hip_bfloat16* __restrict__ cat) {
  int b = blockIdx.x;
  int u = user_idx[b], z = business_idx[b];
  __hip_bfloat16* crow = cat + (size_t)b * 4 * kH;
  for (int c = threadIdx.x; c < kH; c += blockDim.x) {
    crow[c] = __float2bfloat16(xf[(size_t)u * kH + c]);
    crow[kH + c] = __float2bfloat16(xf[(size_t)z * kH + c]);
    crow[2 * kH + c] = __float2bfloat16(text_emb[(size_t)b * kH + c]);
    crow[3 * kH + c] = __float2bfloat16(img_emb[(size_t)b * kH + c]);
  }
}

}  // namespace

extern "C" void kernel_launch(void* const* d_in, const int* in_sizes, int n_in,
                              void* d_out, int out_size, void* d_ws, size_t ws_size,
                              hipStream_t stream) {
  const float* text_cls = (const float*)d_in[0];
  const float* img_cls = (const float*)d_in[1];
  const float* biz_feats = (const float*)d_in[2];
  const float* W_text = (const float*)d_in[3];
  const float* b_text = (const float*)d_in[4];
  const float* W_img = (const float*)d_in[5];
  const float* b_img = (const float*)d_in[6];
  const float* W_bf = (const float*)d_in[7];
  const float* b_bf = (const float*)d_in[8];
  const float* user_table = (const float*)d_in[9];
  const float* biz_table = (const float*)d_in[10];
  const float* W1 = (const float*)d_in[11];
  const float* att_src1 = (const float*)d_in[12];
  const float* att_dst1 = (const float*)d_in[13];
  const float* b1 = (const float*)d_in[14];
  const float* W2 = (const float*)d_in[15];
  const float* att_src2 = (const float*)d_in[16];
  const float* att_dst2 = (const float*)d_in[17];
  const float* b2 = (const float*)d_in[18];
  const float* Wf1 = (const float*)d_in[19];
  const float* bf1 = (const float*)d_in[20];
  const float* Wf2 = (const float*)d_in[21];
  const float* bf2 = (const float*)d_in[22];
  const float* Wf3 = (const float*)d_in[23];
  const float* bf3 = (const float*)d_in[24];
  const int* user_idx = (const int*)d_in[25];
  const int* business_idx = (const int*)d_in[26];
  const int* edge_index = (const int*)d_in[27];
  float* out = (float*)d_out;
  (void)in_sizes; (void)n_in; (void)out_size; (void)ws_size;

  char* base = (char*)d_ws;
  size_t off = 0;
  auto alloc = [&](size_t bytes) -> void* {
    void* p = base + off;
    off = (off + bytes + 255) & ~(size_t)255;
    return p;
  };
  __hip_bfloat16* xb = (__hip_bfloat16*)alloc((size_t)kNN * kH * 2);
  __hip_bfloat16* text_bf = (__hip_bfloat16*)alloc((size_t)kB * kH * 2);
  __hip_bfloat16* imgm_bf = (__hip_bfloat16*)alloc((size_t)kB * kH * 2);
  float* text_emb = (float*)alloc((size_t)kB * kH * 4);
  float* img_emb = (float*)alloc((size_t)kB * kH * 4);
  __hip_bfloat16* Wtt = (__hip_bfloat16*)alloc((size_t)kH * kH * 2);
  __hip_bfloat16* Wit = (__hip_bfloat16*)alloc((size_t)kH * kH * 2);
  __hip_bfloat16* W1t = (__hip_bfloat16*)alloc((size_t)kHeads * kH * kH * 2);
  __hip_bfloat16* W2t = (__hip_bfloat16*)alloc((size_t)kH * kHeads * kH * 2);
  __hip_bfloat16* Wf1t = (__hip_bfloat16*)alloc((size_t)2 * kH * 4 * kH * 2);
  __hip_bfloat16* Wf2t = (__hip_bfloat16*)alloc((size_t)kH * 2 * kH * 2);
  float* wa = (float*)alloc((size_t)2 * kHeads * kH * 4);
  // ---- union region: part (75.5MB) = [y 37.75MB][ext 37.75MB] ----
  // y: live from agg1x to gemm_head.  part: live splitk->reduce_scores2.
  // ext also hosts xf/catb/m1 (live only AFTER part dies).  Wf1/Wf2 partials
  // later reuse the y-subregion (disjoint from ext where their inputs live).
  __hip_bfloat16* y = (__hip_bfloat16*)alloc((size_t)kNN * kHeads * kH * 2);   // 37,748,736 B
  char* ext = (char*)alloc((size_t)kNN * kHeads * kH * 2);                     // 37,748,736 B
  float* part = (float*)y;             // spans y+ext (allocs are contiguous, 256-aligned)
  float* xf = (float*)ext;                                       // 9,437,184 B
  __hip_bfloat16* catb = (__hip_bfloat16*)(ext + 9437184);       // 6,291,456 B
  __hip_bfloat16* m1 = (__hip_bfloat16*)(ext + 9437184 + 6291456);  // 3,145,728 B
  __hip_bfloat16* x2 = (__hip_bfloat16*)alloc((size_t)kNN * kHeads * kH * 2);
  __hip_bfloat16* h2 = (__hip_bfloat16*)alloc((size_t)kNN * kH * 2);
  float* s1s = (float*)alloc((size_t)kNN * kHeads * 4);
  float* s1d = (float*)alloc((size_t)kNN * kHeads * 4);
  float* s2s = (float*)alloc((size_t)kNN * 4);
  float* s2d = (float*)alloc((size_t)kNN * 4);
  int* deg = (int*)alloc((size_t)kNN * 4);
  int* rowptr = (int*)alloc((size_t)(kNN + 1) * 4);
  int* cursor = (int*)alloc((size_t)kNN * 4);
  int* cols = (int*)alloc((size_t)kET * 4);
  int* winner = (int*)alloc((size_t)kNB * 4);

  // mega-kernel: weight transposes + input prep + wa1 + workspace init
  TJobs tj;
  tj.in[0] = W_text; tj.out[0] = Wtt;  tj.K[0] = kH;          tj.N[0] = kH;
  tj.in[1] = W_img;  tj.out[1] = Wit;  tj.K[1] = kH;          tj.N[1] = kH;
  tj.in[2] = W1;     tj.out[2] = W1t;  tj.K[2] = kH;          tj.N[2] = kHeads * kH;
  tj.in[3] = W2;     tj.out[3] = W2t;  tj.K[3] = kHeads * kH; tj.N[3] = kH;
  tj.in[4] = Wf1;    tj.out[4] = Wf1t; tj.K[4] = 4 * kH;      tj.N[4] = 2 * kH;
  tj.in[5] = Wf2;    tj.out[5] = Wf2t; tj.K[5] = 2 * kH;      tj.N[5] = kH;
  tj.start[0] = 0;
  for (int q = 0; q < 6; ++q)
    tj.start[q + 1] = tj.start[q] + (tj.K[q] / 32) * (tj.N[q] / 32);
  const int prep_blocks = (kB * kH + 255) / 256;
  const int wa_blocks = (kHeads * kH) / 4;
  const int init_blocks = (kNN * kH * 2 / 16 + 255) / 256;
  transp_prep_kernel<<<tj.start[6] + prep_blocks + wa_blocks + init_blocks, 256, 0, stream>>>(
      tj, text_cls, img_cls, text_bf, imgm_bf, prep_blocks, W1, att_src1, att_dst1, wa,
      wa_blocks, (uint4*)xb, deg, winner);

  // encoders, batched in z
  mfma_gemm_dual<64, 128, 2, 4><<<dim3(kH / 128, kB / 64, 2), 256, 0, stream>>>(
      text_bf, Wtt, b_text, text_emb, imgm_bf, Wit, b_img, img_emb, kH, kH);

  // CSR degree + winner
  deg_winner_kernel<<<(kET + 255) / 256, 256, 0, stream>>>(edge_index, deg, business_idx, winner);
  scan_kernel<<<1, 1024, 0, stream>>>(deg, rowptr, cursor);
  fill_kernel<<<(kET + 255) / 256, 256, 0, stream>>>(edge_index, cursor, cols);

  // node features
  build_x_kernel<<<kNN, 256, 0, stream>>>(user_idx, user_table, winner, text_emb, img_emb,
                                          biz_feats, W_bf, b_bf, biz_table, xb);

  // GAT layer 1, x-space: scores -> alpha-aggregate (768-dim) -> head-pinned GEMM
  s1_kernel<<<kNN, 256, 0, stream>>>(xb, wa, s1s, s1d);
  agg1x_kernel<<<kNN, 256, 0, stream>>>(rowptr, cols, s1s, s1d, xb, y);
  gemm_head<128, 128, 4, 4><<<dim3(kHeads, (kNN / 128) * (kH / 128)), 256, 0, stream>>>(
      y, W1t, b1, x2);

  // GAT layer 2: K-chunk->XCD-pinned split-K (S=8, 128^2 tile), fused reduce+scores2
  mfma_gemm_kpin<128, 128, 4, 4, kS2>
      <<<dim3(kS2, (kNN / 128) * (kH / 128)), 256, 0, stream>>>(
          x2, W2t, part, kNN, kH, kHeads * kH);
  reduce_scores2_kernel<<<kNN, 192, 0, stream>>>(part, att_src2, att_dst2, h2, s2s, s2d);
  gat_agg_kernel<<<kNN / 4, 256, 0, stream>>>(rowptr, cols, s2s, s2d, h2, b2, xf, kNN);

  // MLP head: cat -> Wf1 (split-K S=2, partials in y-subregion) -> Wf2 -> fused final
  cat_kernel<<<kB, 256, 0, stream>>>(xf, text_emb, img_emb, user_idx, business_idx, catb);
  mfma_gemm_splitk<64, 128, 2, 4><<<dim3(2 * kH / 128, kB / 64, 2), 256, 0, stream>>>(
      catb, Wf1t, (float*)y, kB, 2 * kH, 4 * kH, 2 * kH);
  reduce_relu_kernel<<<(kB * 2 * kH / 4 + 255) / 256, 256, 0, stream>>>(
      (float*)y, bf1, m1, kB * 2 * kH / 4, 2 * kH);
  mfma_gemm_splitk<64, 128, 2, 4><<<dim3(kH / 128, kB / 64, 2), 256, 0, stream>>>(
      m1, Wf2t, (float*)y, kB, kH, 2 * kH, kH);
  reduce_final_kernel<<<kB, 192, 0, stream>>>((float*)y, bf2, Wf3, bf3, out);
}